// Round 9
// baseline (290.995 us; speedup 1.0000x reference)
//
#include <hip/hip_runtime.h>
#include <hip/hip_fp16.h>
#include <math.h>

#define NEG_SLOPE 0.2f
#define BSHIFT 8            // nodes per bucket = 256 (requires N < 65536 for src packing)
#define BCAP 8192           // padded per-bucket edge capacity (mean 4082, sigma 64)

typedef __attribute__((ext_vector_type(8))) short bf16x8;
typedef __attribute__((ext_vector_type(4))) float f32x4;

__device__ __forceinline__ float leaky(float e) {
    return e > 0.f ? e : NEG_SLOPE * e;
}
__device__ __forceinline__ float to_f(float x) { return x; }
__device__ __forceinline__ float to_f(__half x) { return __half2float(x); }

__device__ __forceinline__ unsigned f2bf_bits(float x) {
    unsigned u = __float_as_uint(x);
    return (u + 0x7fffu + ((u >> 16) & 1u)) >> 16;
}

// ---------------- W0 pre-split into bf16 hi/lo, MFMA B-fragment order --------

__device__ __forceinline__ void pack_body_w0(
        int li, const float* __restrict__ W, short* __restrict__ Whi,
        short* __restrict__ Wlo) {
    int k = li >> 6, col = li & 63;
    int c = k >> 5, kin = k & 31;
    int g = col >> 4, nn = col & 15;
    float x = W[li];
    unsigned hb = f2bf_bits(x);
    float hf = __uint_as_float(hb << 16);
    unsigned lb = f2bf_bits(x - hf);
    int o = (((c * 4 + g) * 16 + nn) << 5) + kin;
    Whi[o] = (short)hb;
    Wlo[o] = (short)lb;
}

// ---------------- CSR build: padded-bucket counting sort ---------------------
// int4-vectorized edge reads (4 edges/load); 512 partition blocks keep the
// pass-2 per-bucket global-atomic chains at ~391 deep.

__device__ void partition_body(
        const int* __restrict__ src, const int* __restrict__ dst,
        int* __restrict__ bucketLen, int* __restrict__ pairs, int E, int nbk,
        int pb, int nb) {
    __shared__ int cnt[256];
    __shared__ int run[256];
    int t = threadIdx.x;
    int chunk = (((E + nb - 1) / nb) + 1023) & ~1023;   // multiple of 4*256
    int beg = pb * chunk;
    int end = min(beg + chunk, E);
    if (beg >= end) return;      // block-uniform exit (no divergent barrier)
    cnt[t] = 0;
    __syncthreads();

    const int4* dst4 = (const int4*)dst;
    const int4* src4 = (const int4*)src;
    int vbeg = beg >> 2;
    int vend = end >> 2;                 // beg is 4-aligned by construction
    for (int i = vbeg + t; i < vend; i += 256) {
        int4 d = dst4[i];
        atomicAdd(&cnt[d.x >> BSHIFT], 1);
        atomicAdd(&cnt[d.y >> BSHIFT], 1);
        atomicAdd(&cnt[d.z >> BSHIFT], 1);
        atomicAdd(&cnt[d.w >> BSHIFT], 1);
    }
    for (int i = (vend << 2) + t; i < end; i += 256)
        atomicAdd(&cnt[dst[i] >> BSHIFT], 1);
    __syncthreads();

    if (t < nbk) run[t] = t * BCAP + atomicAdd(&bucketLen[t], cnt[t]);
    __syncthreads();

    for (int i = vbeg + t; i < vend; i += 256) {
        int4 d = dst4[i];
        int4 s = src4[i];
        int b0 = d.x >> BSHIFT, b1 = d.y >> BSHIFT;
        int b2 = d.z >> BSHIFT, b3 = d.w >> BSHIFT;
        int s0 = atomicAdd(&run[b0], 1);
        int s1 = atomicAdd(&run[b1], 1);
        int s2 = atomicAdd(&run[b2], 1);
        int s3 = atomicAdd(&run[b3], 1);
        if (s0 < b0 * BCAP + BCAP) pairs[s0] = (s.x << BSHIFT) | (d.x & 255);
        if (s1 < b1 * BCAP + BCAP) pairs[s1] = (s.y << BSHIFT) | (d.y & 255);
        if (s2 < b2 * BCAP + BCAP) pairs[s2] = (s.z << BSHIFT) | (d.z & 255);
        if (s3 < b3 * BCAP + BCAP) pairs[s3] = (s.w << BSHIFT) | (d.w & 255);
    }
    for (int i = (vend << 2) + t; i < end; i += 256) {
        int d = dst[i];
        int slot = atomicAdd(&run[d >> BSHIFT], 1);
        if (slot < (d >> BSHIFT) * BCAP + BCAP)
            pairs[slot] = (src[i] << BSHIFT) | (d & 255);
    }
}

// fused: blocks [0,32) pack W0; blocks [32, 32+P) partition edges.
__global__ __launch_bounds__(256) void packpart_kernel(
        const float* __restrict__ W0, short* __restrict__ Whi,
        short* __restrict__ Wlo,
        const int* __restrict__ src, const int* __restrict__ dst,
        int* __restrict__ bucketLen, int* __restrict__ pairs, int E, int nbk) {
    if ((int)blockIdx.x < 32) {
        int idx = blockIdx.x * 256 + threadIdx.x;    // 8192 entries
        pack_body_w0(idx, W0, Whi, Wlo);
    } else {
        partition_body(src, dst, bucketLen, pairs, E, nbk,
                       (int)blockIdx.x - 32, (int)gridDim.x - 32);
    }
}

__device__ void csr_build_body(
        int b, const int* __restrict__ bucketLen, const int* __restrict__ pairs,
        int2* __restrict__ offdeg, int* __restrict__ csr_src, int N) {
    __shared__ int degl[256];
    __shared__ int s[256];
    __shared__ int cur[256];
    int t = threadIdx.x;
    int n0 = b << BSHIFT;
    int nodecnt = min(256, N - n0);
    int ebeg = b * BCAP;
    int eend = ebeg + bucketLen[b];

    degl[t] = 0;
    __syncthreads();
    for (int i = ebeg + t; i < eend; i += 256)
        atomicAdd(&degl[pairs[i] & 255], 1);
    __syncthreads();

    int v = degl[t];
    s[t] = v;
    __syncthreads();
    for (int o = 1; o < 256; o <<= 1) {
        int x = (t >= o) ? s[t - o] : 0;
        __syncthreads();
        s[t] += x;
        __syncthreads();
    }
    int excl = s[t] - v;
    if (t < nodecnt)
        offdeg[n0 + t] = make_int2(ebeg + excl, v);
    cur[t] = excl;
    __syncthreads();

    for (int i = ebeg + t; i < eend; i += 256) {
        int pk = pairs[i];
        int p = atomicAdd(&cur[pk & 255], 1);
        csr_src[ebeg + p] = pk >> BSHIFT;
    }
}

// ---------------- layer-0 GEMM + alpha epilogue (MFMA, split-bf16) -----------

template <int CIN, typename InT>
__device__ void gemm_body(
        int bid, const InT* __restrict__ h, const short* __restrict__ Whi,
        const short* __restrict__ Wlo,
        const float* __restrict__ a_src, const float* __restrict__ a_dst,
        __half* __restrict__ hp, float* __restrict__ as_, float* __restrict__ ad_,
        int n) {
    constexpr int KC = CIN / 32;
    int t = threadIdx.x, wave = t >> 6, lane = t & 63;
    int quad = lane >> 4, l16 = lane & 15;
    int node0 = bid * 64 + wave * 16;

    f32x4 acc[4];
#pragma unroll
    for (int g = 0; g < 4; ++g) acc[g] = (f32x4){0.f, 0.f, 0.f, 0.f};

    int nodeA = node0 + l16;
    bool va = nodeA < n;
    const InT* hrow = h + (size_t)(va ? nodeA : 0) * CIN + quad * 8;

#pragma unroll
    for (int c = 0; c < KC; ++c) {
        bf16x8 bhi[4], blo[4];
#pragma unroll
        for (int g = 0; g < 4; ++g) {
            int o = (((c * 4 + g) * 16 + l16) << 5) + quad * 8;
            bhi[g] = *(const bf16x8*)(Whi + o);
            blo[g] = *(const bf16x8*)(Wlo + o);
        }
        bf16x8 ahi, alo;
#pragma unroll
        for (int j = 0; j < 8; ++j) {
            float x = va ? to_f(hrow[c * 32 + j]) : 0.f;
            unsigned hb = f2bf_bits(x);
            float hf = __uint_as_float(hb << 16);
            unsigned lb = f2bf_bits(x - hf);
            ahi[j] = (short)hb;
            alo[j] = (short)lb;
        }
#pragma unroll
        for (int g = 0; g < 4; ++g) {
            acc[g] = __builtin_amdgcn_mfma_f32_16x16x32_bf16(ahi, bhi[g], acc[g], 0, 0, 0);
            acc[g] = __builtin_amdgcn_mfma_f32_16x16x32_bf16(ahi, blo[g], acc[g], 0, 0, 0);
            acc[g] = __builtin_amdgcn_mfma_f32_16x16x32_bf16(alo, bhi[g], acc[g], 0, 0, 0);
        }
    }

    float as4[4], ad4[4];
#pragma unroll
    for (int g = 0; g < 4; ++g) {
        as4[g] = a_src[g * 16 + l16];
        ad4[g] = a_dst[g * 16 + l16];
    }
#pragma unroll
    for (int r = 0; r < 4; ++r) {
        int node = node0 + quad * 4 + r;
        bool v = node < n;
        float vs = 0.f, vd = 0.f;
#pragma unroll
        for (int g = 0; g < 4; ++g) {
            float val = acc[g][r];
            if (v) hp[(size_t)node * 64 + g * 16 + l16] = __float2half_rn(val);
            vs = fmaf(val, as4[g], vs);
            vd = fmaf(val, ad4[g], vd);
        }
#pragma unroll
        for (int o = 1; o <= 8; o <<= 1) {
            vs += __shfl_xor(vs, o);
            vd += __shfl_xor(vd, o);
        }
        if (v && l16 == 0) {
            as_[node] = vs;
            ad_[node] = vd;
        }
    }
}

__global__ __launch_bounds__(256) void csr_gemm0_kernel(
        const int* __restrict__ bucketLen, const int* __restrict__ pairs,
        int2* __restrict__ offdeg, int* __restrict__ csr_src,
        int N, int nbk,
        const float* __restrict__ x, const short* __restrict__ Whi,
        const short* __restrict__ Wlo, const float* __restrict__ a_src,
        const float* __restrict__ a_dst, __half* __restrict__ hp,
        float* __restrict__ as_, float* __restrict__ ad_) {
    if ((int)blockIdx.x < nbk)
        csr_build_body(blockIdx.x, bucketLen, pairs, offdeg, csr_src, N);
    else
        gemm_body<128, float>((int)blockIdx.x - nbk, x, Whi, Wlo,
                              a_src, a_dst, hp, as_, ad_, N);
}

// ---------------- agg (+ fused next-layer GEMM epilogue) ---------------------
// Two nodes per wave (32 lanes each). Critical-path minimized (no-max softmax,
// pre-issued gathers, shfl exchange, hoisted tail operands). The next-layer
// GEMM epilogue reads W DIRECTLY FROM GLOBAL (L2-broadcast; per-k the 32 lanes
// read one contiguous 256-B line; both half-waves hit identical addresses).
// No W LDS tile: saves the 16 KB staging + barrier, frees the LDS pipe
// (previously 64 ds_read_b64/lane/node), and drops block LDS to 1 KB so
// residency is thread-limited (8 blocks/CU), not LDS-limited.

__device__ __forceinline__ void h8_to_f(uint4 u, float* f) {
    __half2 a = *(__half2*)&u.x;
    __half2 b = *(__half2*)&u.y;
    __half2 c = *(__half2*)&u.z;
    __half2 d = *(__half2*)&u.w;
    float2 f01 = __half22float2(a);
    float2 f23 = __half22float2(b);
    float2 f45 = __half22float2(c);
    float2 f67 = __half22float2(d);
    f[0] = f01.x; f[1] = f01.y; f[2] = f23.x; f[3] = f23.y;
    f[4] = f45.x; f[5] = f45.y; f[6] = f67.x; f[7] = f67.y;
}

__device__ __forceinline__ uint4 pack8h(const float* v) {
    __half2 h0 = __floats2half2_rn(v[0], v[1]);
    __half2 h1 = __floats2half2_rn(v[2], v[3]);
    __half2 h2 = __floats2half2_rn(v[4], v[5]);
    __half2 h3 = __floats2half2_rn(v[6], v[7]);
    uint4 u;
    u.x = *(unsigned*)&h0; u.y = *(unsigned*)&h1;
    u.z = *(unsigned*)&h2; u.w = *(unsigned*)&h3;
    return u;
}

template <bool FINAL>
__global__ __launch_bounds__(256) void agg_fused_kernel(
        const __half* __restrict__ hp_in,
        const float* __restrict__ as_in, const float* __restrict__ ad_in,
        const int2* __restrict__ offdeg, const int* __restrict__ csr_src,
        const float* __restrict__ bias,
        const float* __restrict__ Wn,                  // next-layer W, f32 64x64
        const float* __restrict__ asn, const float* __restrict__ adn,
        __half* __restrict__ hp_out, float* __restrict__ as_out,
        float* __restrict__ ad_out, float* __restrict__ final_out, int n) {
    __shared__ __half rowT[8][64];                     // 1 KB (only LDS use)

    int t = threadIdx.x;
    int wave = t >> 6, lane = t & 63;
    int hf = lane >> 5, l32 = lane & 31;
    int node = blockIdx.x * 8 + wave * 2 + hf;
    int slot = wave * 2 + hf;
    if (node >= n) return;

    int2 od = offdeg[node];

    // hoisted tail operands (independent loads; consumed after accumulate)
    float es0 = 0.f, es1 = 0.f, ed0 = 0.f, ed1 = 0.f;
    if constexpr (!FINAL) {
        int c0 = l32 * 2;
        es0 = asn[c0]; es1 = asn[c0 + 1];
        ed0 = adn[c0]; ed1 = adn[c0 + 1];
    }

    int beg = od.x;
    int deg = od.y;
    float adst = ad_in[node];
    float e_self = leaky(as_in[node] + adst);
    float pself = __expf(e_self);

    if (deg <= 32) {
        bool valid = l32 < deg;
        int s = valid ? csr_src[beg + l32] : 0;
        float as_s = valid ? as_in[s] : 0.f;       // critical gather: issue 1st

        int g8 = l32 >> 3, s8 = l32 & 7;
        int base = hf * 32;
        const uint4* hp4 = (const uint4*)hp_in;    // row = 8 x uint4 (64 halves)

        // hoisted bias (all lanes load; only g8==0 consumes)
        const float4* b4p = (const float4*)bias;
        float4 ba = b4p[s8 * 2], bb = b4p[s8 * 2 + 1];

        // ---- pre-issue ALL gather rows (src values via register shfl)
        uint4 u8[8];
#pragma unroll
        for (int q = 0; q < 8; ++q) {
            int jj = g8 + 4 * q;
            int sj = __shfl(s, base + jj);
            if (jj < deg) u8[q] = hp4[(size_t)sj * 8 + s8];
        }
        uint4 uself = (g8 == 0) ? hp4[(size_t)node * 8 + s8]
                                : make_uint4(0u, 0u, 0u, 0u);

        // ---- softmax (no max-shift) — overlaps the in-flight loads
        float p = valid ? __expf(leaky(as_s + adst)) : 0.f;
        float se = p;
#pragma unroll
        for (int o = 16; o > 0; o >>= 1) se += __shfl_xor(se, o);
        se += pself;
        float inv = 1.0f / (se + 1e-16f);
        float pin = p * inv;

        // ---- weighted accumulate (weights via shfl; loads have landed)
        float acc[8];
        float wself = (g8 == 0) ? pself * inv : 0.f;
        {
            float fs[8];
            h8_to_f(uself, fs);
#pragma unroll
            for (int i = 0; i < 8; ++i) acc[i] = wself * fs[i];
        }
#pragma unroll
        for (int q = 0; q < 8; ++q) {
            int jj = g8 + 4 * q;
            float w = __shfl(pin, base + jj);
            if (jj < deg) {
                float f8[8];
                h8_to_f(u8[q], f8);
#pragma unroll
                for (int i = 0; i < 8; ++i) acc[i] = fmaf(w, f8[i], acc[i]);
            }
        }

        // reduce across the 4 groups of this half
#pragma unroll
        for (int i = 0; i < 8; ++i) {
            acc[i] += __shfl_xor(acc[i], 8);
            acc[i] += __shfl_xor(acc[i], 16);
        }

        if (g8 == 0) {
            float v[8];
            v[0] = acc[0] + ba.x; v[1] = acc[1] + ba.y;
            v[2] = acc[2] + ba.z; v[3] = acc[3] + ba.w;
            v[4] = acc[4] + bb.x; v[5] = acc[5] + bb.y;
            v[6] = acc[6] + bb.z; v[7] = acc[7] + bb.w;
#pragma unroll
            for (int i = 0; i < 8; ++i) v[i] = v[i] > 0.f ? v[i] : 0.f;
            if constexpr (FINAL) {
                float4 ra, rb;
                ra.x = v[0]; ra.y = v[1]; ra.z = v[2]; ra.w = v[3];
                rb.x = v[4]; rb.y = v[5]; rb.z = v[6]; rb.w = v[7];
                ((float4*)final_out)[(size_t)node * 16 + s8 * 2] = ra;
                ((float4*)final_out)[(size_t)node * 16 + s8 * 2 + 1] = rb;
            } else {
                ((uint4*)&rowT[slot][0])[s8] = pack8h(v);
            }
        }
    } else {
        // 32-lane strided fallback (P(deg>32) ~ 8e-5 per node); no max-shift
        int end = beg + deg;
        float se = 0.f;
        for (int i = beg + l32; i < end; i += 32) {
            int s = csr_src[i];
            se += __expf(leaky(as_in[s] + adst));
        }
#pragma unroll
        for (int o = 16; o > 0; o >>= 1) se += __shfl_xor(se, o);
        se += pself;
        float inv = 1.0f / (se + 1e-16f);

        const __half2* hpx = (const __half2*)hp_in;   // row = 32 x half2
        float2 hs = __half22float2(hpx[(size_t)node * 32 + l32]);
        float wself = pself * inv;
        float a0 = wself * hs.x, a1 = wself * hs.y;
        for (int i = beg; i < end; ++i) {
            int s = csr_src[i];
            float w = __expf(leaky(as_in[s] + adst)) * inv;
            float2 hv = __half22float2(hpx[(size_t)s * 32 + l32]);
            a0 = fmaf(w, hv.x, a0);
            a1 = fmaf(w, hv.y, a1);
        }
        float r0 = a0 + bias[l32 * 2];
        float r1 = a1 + bias[l32 * 2 + 1];
        r0 = r0 > 0.f ? r0 : 0.f;
        r1 = r1 > 0.f ? r1 : 0.f;
        if constexpr (FINAL) {
            final_out[(size_t)node * 64 + l32 * 2]     = r0;
            final_out[(size_t)node * 64 + l32 * 2 + 1] = r1;
        } else {
            *(__half2*)&rowT[slot][l32 * 2] = __floats2half2_rn(r0, r1);
        }
    }

    // ---- fused next-layer GEMM epilogue (wave-local; W from global/L2) ----
    if constexpr (!FINAL) {
        const float2* W2g = (const float2*)Wn;        // [64][32] float2 view
        const uint4* row4 = (const uint4*)&rowT[slot][0];
        float a0 = 0.f, a1 = 0.f;
#pragma unroll
        for (int kk = 0; kk < 8; ++kk) {
            float f8[8];
            h8_to_f(row4[kk], f8);
#pragma unroll
            for (int j = 0; j < 8; ++j) {
                float2 w = W2g[(kk * 8 + j) * 32 + l32];
                a0 = fmaf(f8[j], w.x, a0);
                a1 = fmaf(f8[j], w.y, a1);
            }
        }
        ((__half2*)hp_out)[(size_t)node * 32 + l32] = __floats2half2_rn(a0, a1);
        float vs = fmaf(a0, es0, a1 * es1);
        float vd = fmaf(a0, ed0, a1 * ed1);
#pragma unroll
        for (int o = 1; o <= 16; o <<= 1) {
            vs += __shfl_xor(vs, o);
            vd += __shfl_xor(vd, o);
        }
        if (l32 == 0) {
            as_out[node] = vs;
            ad_out[node] = vd;
        }
    }
}

// ---------------- launch ----------------

extern "C" void kernel_launch(void* const* d_in, const int* in_sizes, int n_in,
                              void* d_out, int out_size, void* d_ws, size_t ws_size,
                              hipStream_t stream) {
    const float* x = (const float*)d_in[0];
    const int* edge_index = (const int*)d_in[1];
    const int N = in_sizes[0] / 128;
    const int E = in_sizes[1] / 2;
    const int NBK = (N + 255) >> BSHIFT;

    const float* W[3]    = {(const float*)d_in[4], (const float*)d_in[8],  (const float*)d_in[12]};
    const float* asrc[3] = {(const float*)d_in[5], (const float*)d_in[9],  (const float*)d_in[13]};
    const float* adst[3] = {(const float*)d_in[6], (const float*)d_in[10], (const float*)d_in[14]};
    const float* bias[3] = {(const float*)d_in[7], (const float*)d_in[11], (const float*)d_in[15]};

    char* ws = (char*)d_ws;
    size_t o = 0;
    auto alloc = [&](size_t bytes) {
        char* p = ws + o;
        o += (bytes + 255) & ~(size_t)255;
        return p;
    };
    int* bucketLen    = (int*)alloc(256 * 4);
    int* pairs        = (int*)alloc((size_t)NBK * BCAP * 4);
    int2* offdeg      = (int2*)alloc((size_t)N * 8);
    int* csr_src      = (int*)alloc((size_t)NBK * BCAP * 4);
    float* asA        = (float*)alloc((size_t)N * 4);
    float* adA        = (float*)alloc((size_t)N * 4);
    float* asB        = (float*)alloc((size_t)N * 4);
    float* adB        = (float*)alloc((size_t)N * 4);
    __half* hpA       = (__half*)alloc((size_t)N * 64 * 2);
    __half* hpB       = (__half*)alloc((size_t)N * 64 * 2);
    short* Whi        = (short*)alloc(8192 * 2);
    short* Wlo        = (short*)alloc(8192 * 2);

    const int* srcp = edge_index;
    const int* dstp = edge_index + E;

    int gb = (N + 63) / 64;    // 64-node GEMM tiles (layer 0)
    int ab = (N + 7) / 8;      // 8-node agg blocks

    hipMemsetAsync(bucketLen, 0, 256 * sizeof(int), stream);

    // pack W0 || partition edges (independent blocks, one dispatch)
    packpart_kernel<<<32 + 512, 256, 0, stream>>>(
        W[0], Whi, Wlo, srcp, dstp, bucketLen, pairs, E, NBK);

    // csr build || layer-0 GEMM  ->  hpA, asA, adA
    csr_gemm0_kernel<<<NBK + gb, 256, 0, stream>>>(
        bucketLen, pairs, offdeg, csr_src, N, NBK,
        x, Whi, Wlo, asrc[0], adst[0], hpA, asA, adA);

    // agg layer 0 + fused gemm1  ->  hpB, asB, adB
    agg_fused_kernel<false><<<ab, 256, 0, stream>>>(
        hpA, asA, adA, offdeg, csr_src, bias[0],
        W[1], asrc[1], adst[1], hpB, asB, adB, nullptr, N);

    // agg layer 1 + fused gemm2  ->  hpA, asA, adA
    agg_fused_kernel<false><<<ab, 256, 0, stream>>>(
        hpB, asB, adB, offdeg, csr_src, bias[1],
        W[2], asrc[2], adst[2], hpA, asA, adA, nullptr, N);

    // agg layer 2 -> final f32 output
    agg_fused_kernel<true><<<ab, 256, 0, stream>>>(
        hpA, asA, adA, offdeg, csr_src, bias[2],
        nullptr, nullptr, nullptr, nullptr, nullptr, nullptr,
        (float*)d_out, N);
}

// Round 10
// 251.179 us; speedup vs baseline: 1.1585x; 1.1585x over previous
//
#include <hip/hip_runtime.h>
#include <hip/hip_fp16.h>
#include <math.h>

#define NEG_SLOPE 0.2f
#define BSHIFT 8            // nodes per bucket = 256 (requires N < 65536 for src packing)
#define BCAP 8192           // padded per-bucket edge capacity (mean 4082, sigma 64)

typedef __attribute__((ext_vector_type(8))) short bf16x8;
typedef __attribute__((ext_vector_type(4))) float f32x4;

__device__ __forceinline__ float leaky(float e) {
    return e > 0.f ? e : NEG_SLOPE * e;
}
__device__ __forceinline__ float to_f(float x) { return x; }
__device__ __forceinline__ float to_f(__half x) { return __half2float(x); }

__device__ __forceinline__ unsigned f2bf_bits(float x) {
    unsigned u = __float_as_uint(x);
    return (u + 0x7fffu + ((u >> 16) & 1u)) >> 16;
}

// ---------------- W0 pre-split into bf16 hi/lo, MFMA B-fragment order --------

__device__ __forceinline__ void pack_body_w0(
        int li, const float* __restrict__ W, short* __restrict__ Whi,
        short* __restrict__ Wlo) {
    int k = li >> 6, col = li & 63;
    int c = k >> 5, kin = k & 31;
    int g = col >> 4, nn = col & 15;
    float x = W[li];
    unsigned hb = f2bf_bits(x);
    float hf = __uint_as_float(hb << 16);
    unsigned lb = f2bf_bits(x - hf);
    int o = (((c * 4 + g) * 16 + nn) << 5) + kin;
    Whi[o] = (short)hb;
    Wlo[o] = (short)lb;
}

// ---------------- CSR build: padded-bucket counting sort ---------------------
// int4-vectorized edge reads (4 edges/load); 512 partition blocks keep the
// pass-2 per-bucket global-atomic chains at ~391 deep.

__device__ void partition_body(
        const int* __restrict__ src, const int* __restrict__ dst,
        int* __restrict__ bucketLen, int* __restrict__ pairs, int E, int nbk,
        int pb, int nb) {
    __shared__ int cnt[256];
    __shared__ int run[256];
    int t = threadIdx.x;
    int chunk = (((E + nb - 1) / nb) + 1023) & ~1023;   // multiple of 4*256
    int beg = pb * chunk;
    int end = min(beg + chunk, E);
    if (beg >= end) return;      // block-uniform exit (no divergent barrier)
    cnt[t] = 0;
    __syncthreads();

    const int4* dst4 = (const int4*)dst;
    const int4* src4 = (const int4*)src;
    int vbeg = beg >> 2;
    int vend = end >> 2;                 // beg is 4-aligned by construction
    for (int i = vbeg + t; i < vend; i += 256) {
        int4 d = dst4[i];
        atomicAdd(&cnt[d.x >> BSHIFT], 1);
        atomicAdd(&cnt[d.y >> BSHIFT], 1);
        atomicAdd(&cnt[d.z >> BSHIFT], 1);
        atomicAdd(&cnt[d.w >> BSHIFT], 1);
    }
    for (int i = (vend << 2) + t; i < end; i += 256)
        atomicAdd(&cnt[dst[i] >> BSHIFT], 1);
    __syncthreads();

    if (t < nbk) run[t] = t * BCAP + atomicAdd(&bucketLen[t], cnt[t]);
    __syncthreads();

    for (int i = vbeg + t; i < vend; i += 256) {
        int4 d = dst4[i];
        int4 s = src4[i];
        int b0 = d.x >> BSHIFT, b1 = d.y >> BSHIFT;
        int b2 = d.z >> BSHIFT, b3 = d.w >> BSHIFT;
        int s0 = atomicAdd(&run[b0], 1);
        int s1 = atomicAdd(&run[b1], 1);
        int s2 = atomicAdd(&run[b2], 1);
        int s3 = atomicAdd(&run[b3], 1);
        if (s0 < b0 * BCAP + BCAP) pairs[s0] = (s.x << BSHIFT) | (d.x & 255);
        if (s1 < b1 * BCAP + BCAP) pairs[s1] = (s.y << BSHIFT) | (d.y & 255);
        if (s2 < b2 * BCAP + BCAP) pairs[s2] = (s.z << BSHIFT) | (d.z & 255);
        if (s3 < b3 * BCAP + BCAP) pairs[s3] = (s.w << BSHIFT) | (d.w & 255);
    }
    for (int i = (vend << 2) + t; i < end; i += 256) {
        int d = dst[i];
        int slot = atomicAdd(&run[d >> BSHIFT], 1);
        if (slot < (d >> BSHIFT) * BCAP + BCAP)
            pairs[slot] = (src[i] << BSHIFT) | (d & 255);
    }
}

// fused: blocks [0,32) pack W0; blocks [32, 32+P) partition edges.
__global__ __launch_bounds__(256) void packpart_kernel(
        const float* __restrict__ W0, short* __restrict__ Whi,
        short* __restrict__ Wlo,
        const int* __restrict__ src, const int* __restrict__ dst,
        int* __restrict__ bucketLen, int* __restrict__ pairs, int E, int nbk) {
    if ((int)blockIdx.x < 32) {
        int idx = blockIdx.x * 256 + threadIdx.x;    // 8192 entries
        pack_body_w0(idx, W0, Whi, Wlo);
    } else {
        partition_body(src, dst, bucketLen, pairs, E, nbk,
                       (int)blockIdx.x - 32, (int)gridDim.x - 32);
    }
}

__device__ void csr_build_body(
        int b, const int* __restrict__ bucketLen, const int* __restrict__ pairs,
        int2* __restrict__ offdeg, int* __restrict__ csr_src, int N) {
    __shared__ int degl[256];
    __shared__ int s[256];
    __shared__ int cur[256];
    int t = threadIdx.x;
    int n0 = b << BSHIFT;
    int nodecnt = min(256, N - n0);
    int ebeg = b * BCAP;
    int eend = ebeg + bucketLen[b];

    degl[t] = 0;
    __syncthreads();
    for (int i = ebeg + t; i < eend; i += 256)
        atomicAdd(&degl[pairs[i] & 255], 1);
    __syncthreads();

    int v = degl[t];
    s[t] = v;
    __syncthreads();
    for (int o = 1; o < 256; o <<= 1) {
        int x = (t >= o) ? s[t - o] : 0;
        __syncthreads();
        s[t] += x;
        __syncthreads();
    }
    int excl = s[t] - v;
    if (t < nodecnt)
        offdeg[n0 + t] = make_int2(ebeg + excl, v);
    cur[t] = excl;
    __syncthreads();

    for (int i = ebeg + t; i < eend; i += 256) {
        int pk = pairs[i];
        int p = atomicAdd(&cur[pk & 255], 1);
        csr_src[ebeg + p] = pk >> BSHIFT;
    }
}

// ---------------- layer-0 GEMM + alpha epilogue (MFMA, split-bf16) -----------

template <int CIN, typename InT>
__device__ void gemm_body(
        int bid, const InT* __restrict__ h, const short* __restrict__ Whi,
        const short* __restrict__ Wlo,
        const float* __restrict__ a_src, const float* __restrict__ a_dst,
        __half* __restrict__ hp, float* __restrict__ as_, float* __restrict__ ad_,
        int n) {
    constexpr int KC = CIN / 32;
    int t = threadIdx.x, wave = t >> 6, lane = t & 63;
    int quad = lane >> 4, l16 = lane & 15;
    int node0 = bid * 64 + wave * 16;

    f32x4 acc[4];
#pragma unroll
    for (int g = 0; g < 4; ++g) acc[g] = (f32x4){0.f, 0.f, 0.f, 0.f};

    int nodeA = node0 + l16;
    bool va = nodeA < n;
    const InT* hrow = h + (size_t)(va ? nodeA : 0) * CIN + quad * 8;

#pragma unroll
    for (int c = 0; c < KC; ++c) {
        bf16x8 bhi[4], blo[4];
#pragma unroll
        for (int g = 0; g < 4; ++g) {
            int o = (((c * 4 + g) * 16 + l16) << 5) + quad * 8;
            bhi[g] = *(const bf16x8*)(Whi + o);
            blo[g] = *(const bf16x8*)(Wlo + o);
        }
        bf16x8 ahi, alo;
#pragma unroll
        for (int j = 0; j < 8; ++j) {
            float x = va ? to_f(hrow[c * 32 + j]) : 0.f;
            unsigned hb = f2bf_bits(x);
            float hf = __uint_as_float(hb << 16);
            unsigned lb = f2bf_bits(x - hf);
            ahi[j] = (short)hb;
            alo[j] = (short)lb;
        }
#pragma unroll
        for (int g = 0; g < 4; ++g) {
            acc[g] = __builtin_amdgcn_mfma_f32_16x16x32_bf16(ahi, bhi[g], acc[g], 0, 0, 0);
            acc[g] = __builtin_amdgcn_mfma_f32_16x16x32_bf16(ahi, blo[g], acc[g], 0, 0, 0);
            acc[g] = __builtin_amdgcn_mfma_f32_16x16x32_bf16(alo, bhi[g], acc[g], 0, 0, 0);
        }
    }

    float as4[4], ad4[4];
#pragma unroll
    for (int g = 0; g < 4; ++g) {
        as4[g] = a_src[g * 16 + l16];
        ad4[g] = a_dst[g * 16 + l16];
    }
#pragma unroll
    for (int r = 0; r < 4; ++r) {
        int node = node0 + quad * 4 + r;
        bool v = node < n;
        float vs = 0.f, vd = 0.f;
#pragma unroll
        for (int g = 0; g < 4; ++g) {
            float val = acc[g][r];
            if (v) hp[(size_t)node * 64 + g * 16 + l16] = __float2half_rn(val);
            vs = fmaf(val, as4[g], vs);
            vd = fmaf(val, ad4[g], vd);
        }
#pragma unroll
        for (int o = 1; o <= 8; o <<= 1) {
            vs += __shfl_xor(vs, o);
            vd += __shfl_xor(vd, o);
        }
        if (v && l16 == 0) {
            as_[node] = vs;
            ad_[node] = vd;
        }
    }
}

__global__ __launch_bounds__(256) void csr_gemm0_kernel(
        const int* __restrict__ bucketLen, const int* __restrict__ pairs,
        int2* __restrict__ offdeg, int* __restrict__ csr_src,
        int N, int nbk,
        const float* __restrict__ x, const short* __restrict__ Whi,
        const short* __restrict__ Wlo, const float* __restrict__ a_src,
        const float* __restrict__ a_dst, __half* __restrict__ hp,
        float* __restrict__ as_, float* __restrict__ ad_) {
    if ((int)blockIdx.x < nbk)
        csr_build_body(blockIdx.x, bucketLen, pairs, offdeg, csr_src, N);
    else
        gemm_body<128, float>((int)blockIdx.x - nbk, x, Whi, Wlo,
                              a_src, a_dst, hp, as_, ad_, N);
}

// ---------------- agg (+ fused next-layer GEMM epilogue) ---------------------
// TWO nodes per 32-lane half-wave, software-pipelined: ALL loads for both
// nodes (csr_src, as_ logits, 16 hp rows, selves) are issued up front, then
// node A retires, then node B. Doubles memory-level parallelism per wave and
// halves block rounds (grid 6250 -> 3125) — the agg is latency x parallelism
// bound (R7/R8 counters: no saturated pipe, ~0.9 TB/s effective).
// W tile restored to LDS (R8 regression: W-from-global cost 45->72 us).

__device__ __forceinline__ void h8_to_f(uint4 u, float* f) {
    __half2 a = *(__half2*)&u.x;
    __half2 b = *(__half2*)&u.y;
    __half2 c = *(__half2*)&u.z;
    __half2 d = *(__half2*)&u.w;
    float2 f01 = __half22float2(a);
    float2 f23 = __half22float2(b);
    float2 f45 = __half22float2(c);
    float2 f67 = __half22float2(d);
    f[0] = f01.x; f[1] = f01.y; f[2] = f23.x; f[3] = f23.y;
    f[4] = f45.x; f[5] = f45.y; f[6] = f67.x; f[7] = f67.y;
}

__device__ __forceinline__ uint4 pack8h(const float* v) {
    __half2 h0 = __floats2half2_rn(v[0], v[1]);
    __half2 h1 = __floats2half2_rn(v[2], v[3]);
    __half2 h2 = __floats2half2_rn(v[4], v[5]);
    __half2 h3 = __floats2half2_rn(v[6], v[7]);
    uint4 u;
    u.x = *(unsigned*)&h0; u.y = *(unsigned*)&h1;
    u.z = *(unsigned*)&h2; u.w = *(unsigned*)&h3;
    return u;
}

template <bool FINAL>
__global__ __launch_bounds__(256) void agg_fused_kernel(
        const __half* __restrict__ hp_in,
        const float* __restrict__ as_in, const float* __restrict__ ad_in,
        const int2* __restrict__ offdeg, const int* __restrict__ csr_src,
        const float* __restrict__ bias,
        const float* __restrict__ Wn,                  // next-layer W, f32 64x64
        const float* __restrict__ asn, const float* __restrict__ adn,
        __half* __restrict__ hp_out, float* __restrict__ as_out,
        float* __restrict__ ad_out, float* __restrict__ final_out, int n) {
    __shared__ __half rowT[16][64];                    // 2 KB
    __shared__ float Wl[FINAL ? 4 : 4096];             // 16 KB (not FINAL)

    int t = threadIdx.x;
    if constexpr (!FINAL) {
        const float4* wg = (const float4*)Wn;
        float4* wl = (float4*)Wl;
#pragma unroll
        for (int i = 0; i < 4; ++i) wl[t + 256 * i] = wg[t + 256 * i];
        __syncthreads();
    }

    int wave = t >> 6, lane = t & 63;
    int hf = lane >> 5, l32 = lane & 31;
    int pslot = wave * 2 + hf;                 // 0..7
    int nA = blockIdx.x * 16 + pslot * 2;
    int nB = nA + 1;
    if (nA >= n) return;                       // half-uniform; no barriers follow
    bool vB = nB < n;

    // hoisted epilogue operands
    float es0 = 0.f, es1 = 0.f, ed0 = 0.f, ed1 = 0.f;
    if constexpr (!FINAL) {
        int c0 = l32 * 2;
        es0 = asn[c0]; es1 = asn[c0 + 1];
        ed0 = adn[c0]; ed1 = adn[c0 + 1];
    }

    int2 odA = offdeg[nA];
    int2 odB = vB ? offdeg[nB] : make_int2(0, 0);
    float adstA = ad_in[nA];
    float adstB = vB ? ad_in[nB] : 0.f;
    float pselfA = __expf(leaky(as_in[nA] + adstA));
    float pselfB = vB ? __expf(leaky(as_in[nB] + adstB)) : 1.f;

    int g8 = l32 >> 3, s8 = l32 & 7, base = hf * 32;
    const uint4* hp4 = (const uint4*)hp_in;            // row = 8 x uint4
    const float4* b4p = (const float4*)bias;
    float4 ba = b4p[s8 * 2], bb = b4p[s8 * 2 + 1];

    int degA = odA.y, degB = odB.y;

    if (degA <= 32 && degB <= 32) {
        bool valA = l32 < degA;
        bool valB = l32 < degB;
        int sA = valA ? csr_src[odA.x + l32] : 0;
        int sB = valB ? csr_src[odB.x + l32] : 0;
        float as_sA = valA ? as_in[sA] : 0.f;
        float as_sB = valB ? as_in[sB] : 0.f;

        // ---- issue ALL gather rows for BOTH nodes (max in-flight loads)
        uint4 u8A[8], u8B[8];
#pragma unroll
        for (int q = 0; q < 8; ++q) {
            int jj = g8 + 4 * q;
            int sj = __shfl(sA, base + jj);
            if (jj < degA) u8A[q] = hp4[(size_t)sj * 8 + s8];
        }
#pragma unroll
        for (int q = 0; q < 8; ++q) {
            int jj = g8 + 4 * q;
            int sj = __shfl(sB, base + jj);
            if (jj < degB) u8B[q] = hp4[(size_t)sj * 8 + s8];
        }
        uint4 uselfA = (g8 == 0) ? hp4[(size_t)nA * 8 + s8]
                                 : make_uint4(0u, 0u, 0u, 0u);
        uint4 uselfB = (g8 == 0 && vB) ? hp4[(size_t)nB * 8 + s8]
                                       : make_uint4(0u, 0u, 0u, 0u);

        // ---- softmax A and B (overlap the in-flight loads)
        float pA = valA ? __expf(leaky(as_sA + adstA)) : 0.f;
        float seA = pA;
#pragma unroll
        for (int o = 16; o > 0; o >>= 1) seA += __shfl_xor(seA, o);
        seA += pselfA;
        float invA = 1.0f / (seA + 1e-16f);
        float pinA = pA * invA;

        float pB = valB ? __expf(leaky(as_sB + adstB)) : 0.f;
        float seB = pB;
#pragma unroll
        for (int o = 16; o > 0; o >>= 1) seB += __shfl_xor(seB, o);
        seB += pselfB;
        float invB = 1.0f / (seB + 1e-16f);
        float pinB = pB * invB;

        // ---- node A: accumulate, reduce, store
        float acc[8];
        {
            float fs[8];
            h8_to_f(uselfA, fs);
            float w = (g8 == 0) ? pselfA * invA : 0.f;
#pragma unroll
            for (int i = 0; i < 8; ++i) acc[i] = w * fs[i];
        }
#pragma unroll
        for (int q = 0; q < 8; ++q) {
            int jj = g8 + 4 * q;
            float w = __shfl(pinA, base + jj);
            if (jj < degA) {
                float f8[8];
                h8_to_f(u8A[q], f8);
#pragma unroll
                for (int i = 0; i < 8; ++i) acc[i] = fmaf(w, f8[i], acc[i]);
            }
        }
#pragma unroll
        for (int i = 0; i < 8; ++i) {
            acc[i] += __shfl_xor(acc[i], 8);
            acc[i] += __shfl_xor(acc[i], 16);
        }
        if (g8 == 0) {
            float v[8];
            v[0] = acc[0] + ba.x; v[1] = acc[1] + ba.y;
            v[2] = acc[2] + ba.z; v[3] = acc[3] + ba.w;
            v[4] = acc[4] + bb.x; v[5] = acc[5] + bb.y;
            v[6] = acc[6] + bb.z; v[7] = acc[7] + bb.w;
#pragma unroll
            for (int i = 0; i < 8; ++i) v[i] = v[i] > 0.f ? v[i] : 0.f;
            if constexpr (FINAL) {
                float4 ra, rb;
                ra.x = v[0]; ra.y = v[1]; ra.z = v[2]; ra.w = v[3];
                rb.x = v[4]; rb.y = v[5]; rb.z = v[6]; rb.w = v[7];
                ((float4*)final_out)[(size_t)nA * 16 + s8 * 2] = ra;
                ((float4*)final_out)[(size_t)nA * 16 + s8 * 2 + 1] = rb;
            } else {
                ((uint4*)&rowT[pslot * 2][0])[s8] = pack8h(v);
            }
        }

        // ---- node B: accumulate, reduce, store
        {
            float fs[8];
            h8_to_f(uselfB, fs);
            float w = (g8 == 0) ? pselfB * invB : 0.f;
#pragma unroll
            for (int i = 0; i < 8; ++i) acc[i] = w * fs[i];
        }
#pragma unroll
        for (int q = 0; q < 8; ++q) {
            int jj = g8 + 4 * q;
            float w = __shfl(pinB, base + jj);
            if (jj < degB) {
                float f8[8];
                h8_to_f(u8B[q], f8);
#pragma unroll
                for (int i = 0; i < 8; ++i) acc[i] = fmaf(w, f8[i], acc[i]);
            }
        }
#pragma unroll
        for (int i = 0; i < 8; ++i) {
            acc[i] += __shfl_xor(acc[i], 8);
            acc[i] += __shfl_xor(acc[i], 16);
        }
        if (g8 == 0 && vB) {
            float v[8];
            v[0] = acc[0] + ba.x; v[1] = acc[1] + ba.y;
            v[2] = acc[2] + ba.z; v[3] = acc[3] + ba.w;
            v[4] = acc[4] + bb.x; v[5] = acc[5] + bb.y;
            v[6] = acc[6] + bb.z; v[7] = acc[7] + bb.w;
#pragma unroll
            for (int i = 0; i < 8; ++i) v[i] = v[i] > 0.f ? v[i] : 0.f;
            if constexpr (FINAL) {
                float4 ra, rb;
                ra.x = v[0]; ra.y = v[1]; ra.z = v[2]; ra.w = v[3];
                rb.x = v[4]; rb.y = v[5]; rb.z = v[6]; rb.w = v[7];
                ((float4*)final_out)[(size_t)nB * 16 + s8 * 2] = ra;
                ((float4*)final_out)[(size_t)nB * 16 + s8 * 2 + 1] = rb;
            } else {
                ((uint4*)&rowT[pslot * 2 + 1][0])[s8] = pack8h(v);
            }
        }
    } else {
        // rare path: at least one node with deg>32 — process sequentially
        for (int k = 0; k < 2; ++k) {
            if (k == 1 && !vB) break;
            int node = nA + k;
            int2 od = k ? odB : odA;
            float adst = k ? adstB : adstA;
            float pself = k ? pselfB : pselfA;
            int beg = od.x, deg = od.y;
            int slot = pslot * 2 + k;

            if (deg <= 32) {
                bool valid = l32 < deg;
                int s = valid ? csr_src[beg + l32] : 0;
                float as_s = valid ? as_in[s] : 0.f;

                uint4 u8[8];
#pragma unroll
                for (int q = 0; q < 8; ++q) {
                    int jj = g8 + 4 * q;
                    int sj = __shfl(s, base + jj);
                    if (jj < deg) u8[q] = hp4[(size_t)sj * 8 + s8];
                }
                uint4 uself = (g8 == 0) ? hp4[(size_t)node * 8 + s8]
                                        : make_uint4(0u, 0u, 0u, 0u);

                float p = valid ? __expf(leaky(as_s + adst)) : 0.f;
                float se = p;
#pragma unroll
                for (int o = 16; o > 0; o >>= 1) se += __shfl_xor(se, o);
                se += pself;
                float inv = 1.0f / (se + 1e-16f);
                float pin = p * inv;

                float acc[8];
                {
                    float fs[8];
                    h8_to_f(uself, fs);
                    float w = (g8 == 0) ? pself * inv : 0.f;
#pragma unroll
                    for (int i = 0; i < 8; ++i) acc[i] = w * fs[i];
                }
#pragma unroll
                for (int q = 0; q < 8; ++q) {
                    int jj = g8 + 4 * q;
                    float w = __shfl(pin, base + jj);
                    if (jj < deg) {
                        float f8[8];
                        h8_to_f(u8[q], f8);
#pragma unroll
                        for (int i = 0; i < 8; ++i) acc[i] = fmaf(w, f8[i], acc[i]);
                    }
                }
#pragma unroll
                for (int i = 0; i < 8; ++i) {
                    acc[i] += __shfl_xor(acc[i], 8);
                    acc[i] += __shfl_xor(acc[i], 16);
                }
                if (g8 == 0) {
                    float v[8];
                    v[0] = acc[0] + ba.x; v[1] = acc[1] + ba.y;
                    v[2] = acc[2] + ba.z; v[3] = acc[3] + ba.w;
                    v[4] = acc[4] + bb.x; v[5] = acc[5] + bb.y;
                    v[6] = acc[6] + bb.z; v[7] = acc[7] + bb.w;
#pragma unroll
                    for (int i = 0; i < 8; ++i) v[i] = v[i] > 0.f ? v[i] : 0.f;
                    if constexpr (FINAL) {
                        float4 ra, rb;
                        ra.x = v[0]; ra.y = v[1]; ra.z = v[2]; ra.w = v[3];
                        rb.x = v[4]; rb.y = v[5]; rb.z = v[6]; rb.w = v[7];
                        ((float4*)final_out)[(size_t)node * 16 + s8 * 2] = ra;
                        ((float4*)final_out)[(size_t)node * 16 + s8 * 2 + 1] = rb;
                    } else {
                        ((uint4*)&rowT[slot][0])[s8] = pack8h(v);
                    }
                }
            } else {
                // 32-lane strided fallback; no max-shift
                int end = beg + deg;
                float se = 0.f;
                for (int i = beg + l32; i < end; i += 32) {
                    int s = csr_src[i];
                    se += __expf(leaky(as_in[s] + adst));
                }
#pragma unroll
                for (int o = 16; o > 0; o >>= 1) se += __shfl_xor(se, o);
                se += pself;
                float inv = 1.0f / (se + 1e-16f);

                const __half2* hpx = (const __half2*)hp_in;  // row = 32 x half2
                float2 hs = __half22float2(hpx[(size_t)node * 32 + l32]);
                float wself = pself * inv;
                float a0 = wself * hs.x, a1 = wself * hs.y;
                for (int i = beg; i < end; ++i) {
                    int s = csr_src[i];
                    float w = __expf(leaky(as_in[s] + adst)) * inv;
                    float2 hv = __half22float2(hpx[(size_t)s * 32 + l32]);
                    a0 = fmaf(w, hv.x, a0);
                    a1 = fmaf(w, hv.y, a1);
                }
                float r0 = a0 + bias[l32 * 2];
                float r1 = a1 + bias[l32 * 2 + 1];
                r0 = r0 > 0.f ? r0 : 0.f;
                r1 = r1 > 0.f ? r1 : 0.f;
                if constexpr (FINAL) {
                    final_out[(size_t)node * 64 + l32 * 2]     = r0;
                    final_out[(size_t)node * 64 + l32 * 2 + 1] = r1;
                } else {
                    *(__half2*)&rowT[slot][l32 * 2] = __floats2half2_rn(r0, r1);
                }
            }
        }
    }

    // ---- fused next-layer GEMM epilogue (wave-local; W in LDS) ----
    if constexpr (!FINAL) {
        const float2* W2p = (const float2*)Wl;        // [64][32] float2
#pragma unroll
        for (int k = 0; k < 2; ++k) {
            if (k == 1 && !vB) break;
            int node = nA + k;
            const uint4* row4 = (const uint4*)&rowT[pslot * 2 + k][0];
            float a0 = 0.f, a1 = 0.f;
#pragma unroll
            for (int kk = 0; kk < 8; ++kk) {
                float f8[8];
                h8_to_f(row4[kk], f8);
#pragma unroll
                for (int j = 0; j < 8; ++j) {
                    float2 w = W2p[(kk * 8 + j) * 32 + l32];
                    a0 = fmaf(f8[j], w.x, a0);
                    a1 = fmaf(f8[j], w.y, a1);
                }
            }
            ((__half2*)hp_out)[(size_t)node * 32 + l32] = __floats2half2_rn(a0, a1);
            float vs = fmaf(a0, es0, a1 * es1);
            float vd = fmaf(a0, ed0, a1 * ed1);
#pragma unroll
            for (int o = 1; o <= 16; o <<= 1) {
                vs += __shfl_xor(vs, o);
                vd += __shfl_xor(vd, o);
            }
            if (l32 == 0) {
                as_out[node] = vs;
                ad_out[node] = vd;
            }
        }
    }
}

// ---------------- launch ----------------

extern "C" void kernel_launch(void* const* d_in, const int* in_sizes, int n_in,
                              void* d_out, int out_size, void* d_ws, size_t ws_size,
                              hipStream_t stream) {
    const float* x = (const float*)d_in[0];
    const int* edge_index = (const int*)d_in[1];
    const int N = in_sizes[0] / 128;
    const int E = in_sizes[1] / 2;
    const int NBK = (N + 255) >> BSHIFT;

    const float* W[3]    = {(const float*)d_in[4], (const float*)d_in[8],  (const float*)d_in[12]};
    const float* asrc[3] = {(const float*)d_in[5], (const float*)d_in[9],  (const float*)d_in[13]};
    const float* adst[3] = {(const float*)d_in[6], (const float*)d_in[10], (const float*)d_in[14]};
    const float* bias[3] = {(const float*)d_in[7], (const float*)d_in[11], (const float*)d_in[15]};

    char* ws = (char*)d_ws;
    size_t o = 0;
    auto alloc = [&](size_t bytes) {
        char* p = ws + o;
        o += (bytes + 255) & ~(size_t)255;
        return p;
    };
    int* bucketLen    = (int*)alloc(256 * 4);
    int* pairs        = (int*)alloc((size_t)NBK * BCAP * 4);
    int2* offdeg      = (int2*)alloc((size_t)N * 8);
    int* csr_src      = (int*)alloc((size_t)NBK * BCAP * 4);
    float* asA        = (float*)alloc((size_t)N * 4);
    float* adA        = (float*)alloc((size_t)N * 4);
    float* asB        = (float*)alloc((size_t)N * 4);
    float* adB        = (float*)alloc((size_t)N * 4);
    __half* hpA       = (__half*)alloc((size_t)N * 64 * 2);
    __half* hpB       = (__half*)alloc((size_t)N * 64 * 2);
    short* Whi        = (short*)alloc(8192 * 2);
    short* Wlo        = (short*)alloc(8192 * 2);

    const int* srcp = edge_index;
    const int* dstp = edge_index + E;

    int gb = (N + 63) / 64;     // 64-node GEMM tiles (layer 0)
    int ab = (N + 15) / 16;     // 16-node agg blocks (2 nodes per half-wave)

    hipMemsetAsync(bucketLen, 0, 256 * sizeof(int), stream);

    // pack W0 || partition edges (independent blocks, one dispatch)
    packpart_kernel<<<32 + 512, 256, 0, stream>>>(
        W[0], Whi, Wlo, srcp, dstp, bucketLen, pairs, E, NBK);

    // csr build || layer-0 GEMM  ->  hpA, asA, adA
    csr_gemm0_kernel<<<NBK + gb, 256, 0, stream>>>(
        bucketLen, pairs, offdeg, csr_src, N, NBK,
        x, Whi, Wlo, asrc[0], adst[0], hpA, asA, adA);

    // agg layer 0 + fused gemm1  ->  hpB, asB, adB
    agg_fused_kernel<false><<<ab, 256, 0, stream>>>(
        hpA, asA, adA, offdeg, csr_src, bias[0],
        W[1], asrc[1], adst[1], hpB, asB, adB, nullptr, N);

    // agg layer 1 + fused gemm2  ->  hpA, asA, adA
    agg_fused_kernel<false><<<ab, 256, 0, stream>>>(
        hpB, asB, adB, offdeg, csr_src, bias[1],
        W[2], asrc[2], adst[2], hpA, asA, adA, nullptr, N);

    // agg layer 2 -> final f32 output
    agg_fused_kernel<true><<<ab, 256, 0, stream>>>(
        hpA, asA, adA, offdeg, csr_src, bias[2],
        nullptr, nullptr, nullptr, nullptr, nullptr, nullptr,
        (float*)d_out, N);
}

// Round 11
// 248.630 us; speedup vs baseline: 1.1704x; 1.0102x over previous
//
#include <hip/hip_runtime.h>
#include <hip/hip_fp16.h>
#include <math.h>

#define NEG_SLOPE 0.2f
#define BSHIFT 8            // nodes per bucket = 256 (requires N < 65536 for src packing)
#define BCAP 8192           // padded per-bucket edge capacity (mean 4082, sigma 64)

typedef __attribute__((ext_vector_type(8))) short bf16x8;
typedef __attribute__((ext_vector_type(4))) float f32x4;

__device__ __forceinline__ float leaky(float e) {
    return e > 0.f ? e : NEG_SLOPE * e;
}
__device__ __forceinline__ float to_f(float x) { return x; }
__device__ __forceinline__ float to_f(__half x) { return __half2float(x); }

__device__ __forceinline__ unsigned f2bf_bits(float x) {
    unsigned u = __float_as_uint(x);
    return (u + 0x7fffu + ((u >> 16) & 1u)) >> 16;
}

// ---------------- W0 pre-split into bf16 hi/lo, MFMA B-fragment order --------

__device__ __forceinline__ void pack_body_w0(
        int li, const float* __restrict__ W, short* __restrict__ Whi,
        short* __restrict__ Wlo) {
    int k = li >> 6, col = li & 63;
    int c = k >> 5, kin = k & 31;
    int g = col >> 4, nn = col & 15;
    float x = W[li];
    unsigned hb = f2bf_bits(x);
    float hf = __uint_as_float(hb << 16);
    unsigned lb = f2bf_bits(x - hf);
    int o = (((c * 4 + g) * 16 + nn) << 5) + kin;
    Whi[o] = (short)hb;
    Wlo[o] = (short)lb;
}

// ---------------- CSR build: padded-bucket counting sort ---------------------
// int4-vectorized edge reads (4 edges/load); 512 partition blocks keep the
// pass-2 per-bucket global-atomic chains at ~391 deep.

__device__ void partition_body(
        const int* __restrict__ src, const int* __restrict__ dst,
        int* __restrict__ bucketLen, int* __restrict__ pairs, int E, int nbk,
        int pb, int nb) {
    __shared__ int cnt[256];
    __shared__ int run[256];
    int t = threadIdx.x;
    int chunk = (((E + nb - 1) / nb) + 1023) & ~1023;   // multiple of 4*256
    int beg = pb * chunk;
    int end = min(beg + chunk, E);
    if (beg >= end) return;      // block-uniform exit (no divergent barrier)
    cnt[t] = 0;
    __syncthreads();

    const int4* dst4 = (const int4*)dst;
    const int4* src4 = (const int4*)src;
    int vbeg = beg >> 2;
    int vend = end >> 2;                 // beg is 4-aligned by construction
    for (int i = vbeg + t; i < vend; i += 256) {
        int4 d = dst4[i];
        atomicAdd(&cnt[d.x >> BSHIFT], 1);
        atomicAdd(&cnt[d.y >> BSHIFT], 1);
        atomicAdd(&cnt[d.z >> BSHIFT], 1);
        atomicAdd(&cnt[d.w >> BSHIFT], 1);
    }
    for (int i = (vend << 2) + t; i < end; i += 256)
        atomicAdd(&cnt[dst[i] >> BSHIFT], 1);
    __syncthreads();

    if (t < nbk) run[t] = t * BCAP + atomicAdd(&bucketLen[t], cnt[t]);
    __syncthreads();

    for (int i = vbeg + t; i < vend; i += 256) {
        int4 d = dst4[i];
        int4 s = src4[i];
        int b0 = d.x >> BSHIFT, b1 = d.y >> BSHIFT;
        int b2 = d.z >> BSHIFT, b3 = d.w >> BSHIFT;
        int s0 = atomicAdd(&run[b0], 1);
        int s1 = atomicAdd(&run[b1], 1);
        int s2 = atomicAdd(&run[b2], 1);
        int s3 = atomicAdd(&run[b3], 1);
        if (s0 < b0 * BCAP + BCAP) pairs[s0] = (s.x << BSHIFT) | (d.x & 255);
        if (s1 < b1 * BCAP + BCAP) pairs[s1] = (s.y << BSHIFT) | (d.y & 255);
        if (s2 < b2 * BCAP + BCAP) pairs[s2] = (s.z << BSHIFT) | (d.z & 255);
        if (s3 < b3 * BCAP + BCAP) pairs[s3] = (s.w << BSHIFT) | (d.w & 255);
    }
    for (int i = (vend << 2) + t; i < end; i += 256) {
        int d = dst[i];
        int slot = atomicAdd(&run[d >> BSHIFT], 1);
        if (slot < (d >> BSHIFT) * BCAP + BCAP)
            pairs[slot] = (src[i] << BSHIFT) | (d & 255);
    }
}

// fused: blocks [0,32) pack W0; blocks [32, 32+P) partition edges.
__global__ __launch_bounds__(256) void packpart_kernel(
        const float* __restrict__ W0, short* __restrict__ Whi,
        short* __restrict__ Wlo,
        const int* __restrict__ src, const int* __restrict__ dst,
        int* __restrict__ bucketLen, int* __restrict__ pairs, int E, int nbk) {
    if ((int)blockIdx.x < 32) {
        int idx = blockIdx.x * 256 + threadIdx.x;    // 8192 entries
        pack_body_w0(idx, W0, Whi, Wlo);
    } else {
        partition_body(src, dst, bucketLen, pairs, E, nbk,
                       (int)blockIdx.x - 32, (int)gridDim.x - 32);
    }
}

__device__ void csr_build_body(
        int b, const int* __restrict__ bucketLen, const int* __restrict__ pairs,
        int2* __restrict__ offdeg, int* __restrict__ csr_src, int N) {
    __shared__ int degl[256];
    __shared__ int s[256];
    __shared__ int cur[256];
    int t = threadIdx.x;
    int n0 = b << BSHIFT;
    int nodecnt = min(256, N - n0);
    int ebeg = b * BCAP;
    int eend = ebeg + bucketLen[b];

    degl[t] = 0;
    __syncthreads();
    for (int i = ebeg + t; i < eend; i += 256)
        atomicAdd(&degl[pairs[i] & 255], 1);
    __syncthreads();

    int v = degl[t];
    s[t] = v;
    __syncthreads();
    for (int o = 1; o < 256; o <<= 1) {
        int x = (t >= o) ? s[t - o] : 0;
        __syncthreads();
        s[t] += x;
        __syncthreads();
    }
    int excl = s[t] - v;
    if (t < nodecnt)
        offdeg[n0 + t] = make_int2(ebeg + excl, v);
    cur[t] = excl;
    __syncthreads();

    for (int i = ebeg + t; i < eend; i += 256) {
        int pk = pairs[i];
        int p = atomicAdd(&cur[pk & 255], 1);
        csr_src[ebeg + p] = pk >> BSHIFT;
    }
}

// ---------------- layer-0 GEMM + alpha epilogue (MFMA, split-bf16) -----------

template <int CIN, typename InT>
__device__ void gemm_body(
        int bid, const InT* __restrict__ h, const short* __restrict__ Whi,
        const short* __restrict__ Wlo,
        const float* __restrict__ a_src, const float* __restrict__ a_dst,
        __half* __restrict__ hp, float* __restrict__ as_, float* __restrict__ ad_,
        int n) {
    constexpr int KC = CIN / 32;
    int t = threadIdx.x, wave = t >> 6, lane = t & 63;
    int quad = lane >> 4, l16 = lane & 15;
    int node0 = bid * 64 + wave * 16;

    f32x4 acc[4];
#pragma unroll
    for (int g = 0; g < 4; ++g) acc[g] = (f32x4){0.f, 0.f, 0.f, 0.f};

    int nodeA = node0 + l16;
    bool va = nodeA < n;
    const InT* hrow = h + (size_t)(va ? nodeA : 0) * CIN + quad * 8;

#pragma unroll
    for (int c = 0; c < KC; ++c) {
        bf16x8 bhi[4], blo[4];
#pragma unroll
        for (int g = 0; g < 4; ++g) {
            int o = (((c * 4 + g) * 16 + l16) << 5) + quad * 8;
            bhi[g] = *(const bf16x8*)(Whi + o);
            blo[g] = *(const bf16x8*)(Wlo + o);
        }
        bf16x8 ahi, alo;
#pragma unroll
        for (int j = 0; j < 8; ++j) {
            float x = va ? to_f(hrow[c * 32 + j]) : 0.f;
            unsigned hb = f2bf_bits(x);
            float hf = __uint_as_float(hb << 16);
            unsigned lb = f2bf_bits(x - hf);
            ahi[j] = (short)hb;
            alo[j] = (short)lb;
        }
#pragma unroll
        for (int g = 0; g < 4; ++g) {
            acc[g] = __builtin_amdgcn_mfma_f32_16x16x32_bf16(ahi, bhi[g], acc[g], 0, 0, 0);
            acc[g] = __builtin_amdgcn_mfma_f32_16x16x32_bf16(ahi, blo[g], acc[g], 0, 0, 0);
            acc[g] = __builtin_amdgcn_mfma_f32_16x16x32_bf16(alo, bhi[g], acc[g], 0, 0, 0);
        }
    }

    float as4[4], ad4[4];
#pragma unroll
    for (int g = 0; g < 4; ++g) {
        as4[g] = a_src[g * 16 + l16];
        ad4[g] = a_dst[g * 16 + l16];
    }
#pragma unroll
    for (int r = 0; r < 4; ++r) {
        int node = node0 + quad * 4 + r;
        bool v = node < n;
        float vs = 0.f, vd = 0.f;
#pragma unroll
        for (int g = 0; g < 4; ++g) {
            float val = acc[g][r];
            if (v) hp[(size_t)node * 64 + g * 16 + l16] = __float2half_rn(val);
            vs = fmaf(val, as4[g], vs);
            vd = fmaf(val, ad4[g], vd);
        }
#pragma unroll
        for (int o = 1; o <= 8; o <<= 1) {
            vs += __shfl_xor(vs, o);
            vd += __shfl_xor(vd, o);
        }
        if (v && l16 == 0) {
            as_[node] = vs;
            ad_[node] = vd;
        }
    }
}

__global__ __launch_bounds__(256) void csr_gemm0_kernel(
        const int* __restrict__ bucketLen, const int* __restrict__ pairs,
        int2* __restrict__ offdeg, int* __restrict__ csr_src,
        int N, int nbk,
        const float* __restrict__ x, const short* __restrict__ Whi,
        const short* __restrict__ Wlo, const float* __restrict__ a_src,
        const float* __restrict__ a_dst, __half* __restrict__ hp,
        float* __restrict__ as_, float* __restrict__ ad_) {
    if ((int)blockIdx.x < nbk)
        csr_build_body(blockIdx.x, bucketLen, pairs, offdeg, csr_src, N);
    else
        gemm_body<128, float>((int)blockIdx.x - nbk, x, Whi, Wlo,
                              a_src, a_dst, hp, as_, ad_, N);
}

// ---------------- agg (+ fused next-layer GEMM epilogue) ---------------------
// Round-7 inner loop (verified best: 1 node per 32-lane half-wave, no-max
// softmax, pre-issued gathers, shfl exchange, hoisted tail operands, W in
// LDS). New this round:
//  - 512-thread blocks (16 nodes): halves block count -> W staging traffic
//    100 -> 50 MB/dispatch.
//  - deferred staging barrier: W global loads issued into REGISTERS at kernel
//    start, agg runs, then LDS-write + one __syncthreads right before the
//    epilogue — staging latency hides under the agg phase instead of
//    stalling each block's start. Early return replaced by `active` guard so
//    the barrier stays uniform.

__device__ __forceinline__ void h8_to_f(uint4 u, float* f) {
    __half2 a = *(__half2*)&u.x;
    __half2 b = *(__half2*)&u.y;
    __half2 c = *(__half2*)&u.z;
    __half2 d = *(__half2*)&u.w;
    float2 f01 = __half22float2(a);
    float2 f23 = __half22float2(b);
    float2 f45 = __half22float2(c);
    float2 f67 = __half22float2(d);
    f[0] = f01.x; f[1] = f01.y; f[2] = f23.x; f[3] = f23.y;
    f[4] = f45.x; f[5] = f45.y; f[6] = f67.x; f[7] = f67.y;
}

__device__ __forceinline__ uint4 pack8h(const float* v) {
    __half2 h0 = __floats2half2_rn(v[0], v[1]);
    __half2 h1 = __floats2half2_rn(v[2], v[3]);
    __half2 h2 = __floats2half2_rn(v[4], v[5]);
    __half2 h3 = __floats2half2_rn(v[6], v[7]);
    uint4 u;
    u.x = *(unsigned*)&h0; u.y = *(unsigned*)&h1;
    u.z = *(unsigned*)&h2; u.w = *(unsigned*)&h3;
    return u;
}

template <bool FINAL>
__global__ __launch_bounds__(512) void agg_fused_kernel(
        const __half* __restrict__ hp_in,
        const float* __restrict__ as_in, const float* __restrict__ ad_in,
        const int2* __restrict__ offdeg, const int* __restrict__ csr_src,
        const float* __restrict__ bias,
        const float* __restrict__ Wn,                  // next-layer W, f32 64x64
        const float* __restrict__ asn, const float* __restrict__ adn,
        __half* __restrict__ hp_out, float* __restrict__ as_out,
        float* __restrict__ ad_out, float* __restrict__ final_out, int n) {
    __shared__ __half rowT[16][64];                    // 2 KB
    __shared__ float Wl[FINAL ? 4 : 4096];             // 16 KB (not FINAL)

    int t = threadIdx.x;

    // issue W loads into registers (latency hides under the agg phase)
    float4 wreg0, wreg1;
    if constexpr (!FINAL) {
        const float4* wg = (const float4*)Wn;          // 1024 float4 total
        wreg0 = wg[t];
        wreg1 = wg[t + 512];
    }

    int wave = t >> 6, lane = t & 63;
    int hf = lane >> 5, l32 = lane & 31;
    int slot = wave * 2 + hf;                          // 0..15
    int node = blockIdx.x * 16 + slot;
    bool active = node < n;

    if (active) {
        int2 od = offdeg[node];

        // hoisted epilogue operands
        int beg = od.x;
        int deg = od.y;
        float adst = ad_in[node];
        float e_self = leaky(as_in[node] + adst);
        float pself = __expf(e_self);

        if (deg <= 32) {
            bool valid = l32 < deg;
            int s = valid ? csr_src[beg + l32] : 0;
            float as_s = valid ? as_in[s] : 0.f;   // critical gather: issue 1st

            int g8 = l32 >> 3, s8 = l32 & 7;
            int base = hf * 32;
            const uint4* hp4 = (const uint4*)hp_in;  // row = 8 x uint4

            // hoisted bias (all lanes load; only g8==0 consumes)
            const float4* b4p = (const float4*)bias;
            float4 ba = b4p[s8 * 2], bb = b4p[s8 * 2 + 1];

            // ---- pre-issue ALL gather rows (src values via register shfl)
            uint4 u8[8];
#pragma unroll
            for (int q = 0; q < 8; ++q) {
                int jj = g8 + 4 * q;
                int sj = __shfl(s, base + jj);
                if (jj < deg) u8[q] = hp4[(size_t)sj * 8 + s8];
            }
            uint4 uself = (g8 == 0) ? hp4[(size_t)node * 8 + s8]
                                    : make_uint4(0u, 0u, 0u, 0u);

            // ---- softmax (no max-shift) — overlaps the in-flight loads
            float p = valid ? __expf(leaky(as_s + adst)) : 0.f;
            float se = p;
#pragma unroll
            for (int o = 16; o > 0; o >>= 1) se += __shfl_xor(se, o);
            se += pself;
            float inv = 1.0f / (se + 1e-16f);
            float pin = p * inv;

            // ---- weighted accumulate (weights via shfl; loads have landed)
            float acc[8];
            float wself = (g8 == 0) ? pself * inv : 0.f;
            {
                float fs[8];
                h8_to_f(uself, fs);
#pragma unroll
                for (int i = 0; i < 8; ++i) acc[i] = wself * fs[i];
            }
#pragma unroll
            for (int q = 0; q < 8; ++q) {
                int jj = g8 + 4 * q;
                float w = __shfl(pin, base + jj);
                if (jj < deg) {
                    float f8[8];
                    h8_to_f(u8[q], f8);
#pragma unroll
                    for (int i = 0; i < 8; ++i) acc[i] = fmaf(w, f8[i], acc[i]);
                }
            }

            // reduce across the 4 groups of this half
#pragma unroll
            for (int i = 0; i < 8; ++i) {
                acc[i] += __shfl_xor(acc[i], 8);
                acc[i] += __shfl_xor(acc[i], 16);
            }

            if (g8 == 0) {
                float v[8];
                v[0] = acc[0] + ba.x; v[1] = acc[1] + ba.y;
                v[2] = acc[2] + ba.z; v[3] = acc[3] + ba.w;
                v[4] = acc[4] + bb.x; v[5] = acc[5] + bb.y;
                v[6] = acc[6] + bb.z; v[7] = acc[7] + bb.w;
#pragma unroll
                for (int i = 0; i < 8; ++i) v[i] = v[i] > 0.f ? v[i] : 0.f;
                if constexpr (FINAL) {
                    float4 ra, rb;
                    ra.x = v[0]; ra.y = v[1]; ra.z = v[2]; ra.w = v[3];
                    rb.x = v[4]; rb.y = v[5]; rb.z = v[6]; rb.w = v[7];
                    ((float4*)final_out)[(size_t)node * 16 + s8 * 2] = ra;
                    ((float4*)final_out)[(size_t)node * 16 + s8 * 2 + 1] = rb;
                } else {
                    ((uint4*)&rowT[slot][0])[s8] = pack8h(v);
                }
            }
        } else {
            // 32-lane strided fallback (P(deg>32) ~ 8e-5 per node)
            int end = beg + deg;
            float se = 0.f;
            for (int i = beg + l32; i < end; i += 32) {
                int s = csr_src[i];
                se += __expf(leaky(as_in[s] + adst));
            }
#pragma unroll
            for (int o = 16; o > 0; o >>= 1) se += __shfl_xor(se, o);
            se += pself;
            float inv = 1.0f / (se + 1e-16f);

            const __half2* hpx = (const __half2*)hp_in;   // row = 32 x half2
            float2 hs = __half22float2(hpx[(size_t)node * 32 + l32]);
            float wself = pself * inv;
            float a0 = wself * hs.x, a1 = wself * hs.y;
            for (int i = beg; i < end; ++i) {
                int s = csr_src[i];
                float w = __expf(leaky(as_in[s] + adst)) * inv;
                float2 hv = __half22float2(hpx[(size_t)s * 32 + l32]);
                a0 = fmaf(w, hv.x, a0);
                a1 = fmaf(w, hv.y, a1);
            }
            float r0 = a0 + bias[l32 * 2];
            float r1 = a1 + bias[l32 * 2 + 1];
            r0 = r0 > 0.f ? r0 : 0.f;
            r1 = r1 > 0.f ? r1 : 0.f;
            if constexpr (FINAL) {
                final_out[(size_t)node * 64 + l32 * 2]     = r0;
                final_out[(size_t)node * 64 + l32 * 2 + 1] = r1;
            } else {
                *(__half2*)&rowT[slot][l32 * 2] = __floats2half2_rn(r0, r1);
            }
        }
    }

    // ---- commit W to LDS + uniform barrier, then GEMM epilogue ----
    if constexpr (!FINAL) {
        float4* wl = (float4*)Wl;
        wl[t] = wreg0;
        wl[t + 512] = wreg1;
        __syncthreads();

        if (active) {
            int c0 = l32 * 2;
            float es0 = asn[c0], es1 = asn[c0 + 1];
            float ed0 = adn[c0], ed1 = adn[c0 + 1];
            const float2* W2p = (const float2*)Wl;        // [64][32] float2
            const uint4* row4 = (const uint4*)&rowT[slot][0];
            float a0 = 0.f, a1 = 0.f;
#pragma unroll
            for (int kk = 0; kk < 8; ++kk) {
                float f8[8];
                h8_to_f(row4[kk], f8);
#pragma unroll
                for (int j = 0; j < 8; ++j) {
                    float2 w = W2p[(kk * 8 + j) * 32 + l32];
                    a0 = fmaf(f8[j], w.x, a0);
                    a1 = fmaf(f8[j], w.y, a1);
                }
            }
            ((__half2*)hp_out)[(size_t)node * 32 + l32] = __floats2half2_rn(a0, a1);
            float vs = fmaf(a0, es0, a1 * es1);
            float vd = fmaf(a0, ed0, a1 * ed1);
#pragma unroll
            for (int o = 1; o <= 16; o <<= 1) {
                vs += __shfl_xor(vs, o);
                vd += __shfl_xor(vd, o);
            }
            if (l32 == 0) {
                as_out[node] = vs;
                ad_out[node] = vd;
            }
        }
    }
}

// ---------------- launch ----------------

extern "C" void kernel_launch(void* const* d_in, const int* in_sizes, int n_in,
                              void* d_out, int out_size, void* d_ws, size_t ws_size,
                              hipStream_t stream) {
    const float* x = (const float*)d_in[0];
    const int* edge_index = (const int*)d_in[1];
    const int N = in_sizes[0] / 128;
    const int E = in_sizes[1] / 2;
    const int NBK = (N + 255) >> BSHIFT;

    const float* W[3]    = {(const float*)d_in[4], (const float*)d_in[8],  (const float*)d_in[12]};
    const float* asrc[3] = {(const float*)d_in[5], (const float*)d_in[9],  (const float*)d_in[13]};
    const float* adst[3] = {(const float*)d_in[6], (const float*)d_in[10], (const float*)d_in[14]};
    const float* bias[3] = {(const float*)d_in[7], (const float*)d_in[11], (const float*)d_in[15]};

    char* ws = (char*)d_ws;
    size_t o = 0;
    auto alloc = [&](size_t bytes) {
        char* p = ws + o;
        o += (bytes + 255) & ~(size_t)255;
        return p;
    };
    int* bucketLen    = (int*)alloc(256 * 4);
    int* pairs        = (int*)alloc((size_t)NBK * BCAP * 4);
    int2* offdeg      = (int2*)alloc((size_t)N * 8);
    int* csr_src      = (int*)alloc((size_t)NBK * BCAP * 4);
    float* asA        = (float*)alloc((size_t)N * 4);
    float* adA        = (float*)alloc((size_t)N * 4);
    float* asB        = (float*)alloc((size_t)N * 4);
    float* adB        = (float*)alloc((size_t)N * 4);
    __half* hpA       = (__half*)alloc((size_t)N * 64 * 2);
    __half* hpB       = (__half*)alloc((size_t)N * 64 * 2);
    short* Whi        = (short*)alloc(8192 * 2);
    short* Wlo        = (short*)alloc(8192 * 2);

    const int* srcp = edge_index;
    const int* dstp = edge_index + E;

    int gb = (N + 63) / 64;     // 64-node GEMM tiles (layer 0)
    int ab = (N + 15) / 16;     // 16-node agg blocks (512 threads)

    hipMemsetAsync(bucketLen, 0, 256 * sizeof(int), stream);

    // pack W0 || partition edges (independent blocks, one dispatch)
    packpart_kernel<<<32 + 512, 256, 0, stream>>>(
        W[0], Whi, Wlo, srcp, dstp, bucketLen, pairs, E, NBK);

    // csr build || layer-0 GEMM  ->  hpA, asA, adA
    csr_gemm0_kernel<<<NBK + gb, 256, 0, stream>>>(
        bucketLen, pairs, offdeg, csr_src, N, NBK,
        x, Whi, Wlo, asrc[0], adst[0], hpA, asA, adA);

    // agg layer 0 + fused gemm1  ->  hpB, asB, adB
    agg_fused_kernel<false><<<ab, 512, 0, stream>>>(
        hpA, asA, adA, offdeg, csr_src, bias[0],
        W[1], asrc[1], adst[1], hpB, asB, adB, nullptr, N);

    // agg layer 1 + fused gemm2  ->  hpA, asA, adA
    agg_fused_kernel<false><<<ab, 512, 0, stream>>>(
        hpB, asB, adB, offdeg, csr_src, bias[1],
        W[2], asrc[2], adst[2], hpA, asA, adA, nullptr, N);

    // agg layer 2 -> final f32 output
    agg_fused_kernel<true><<<ab, 512, 0, stream>>>(
        hpA, asA, adA, offdeg, csr_src, bias[2],
        nullptr, nullptr, nullptr, nullptr, nullptr, nullptr,
        (float*)d_out, N);
}

// Round 12
// 239.644 us; speedup vs baseline: 1.2143x; 1.0375x over previous
//
#include <hip/hip_runtime.h>
#include <hip/hip_fp16.h>
#include <math.h>

#define NEG_SLOPE 0.2f
#define BSHIFT 8            // nodes per bucket = 256 (requires N < 65536 for src packing)
#define BCAP 8192           // padded per-bucket edge capacity (mean 4082, sigma 64)

typedef __attribute__((ext_vector_type(8))) short bf16x8;
typedef __attribute__((ext_vector_type(4))) float f32x4;

__device__ __forceinline__ float leaky(float e) {
    return e > 0.f ? e : NEG_SLOPE * e;
}
__device__ __forceinline__ float to_f(float x) { return x; }
__device__ __forceinline__ float to_f(__half x) { return __half2float(x); }

__device__ __forceinline__ unsigned f2bf_bits(float x) {
    unsigned u = __float_as_uint(x);
    return (u + 0x7fffu + ((u >> 16) & 1u)) >> 16;
}

// ---------------- W0 pre-split into bf16 hi/lo, MFMA B-fragment order --------

__device__ __forceinline__ void pack_body_w0(
        int li, const float* __restrict__ W, short* __restrict__ Whi,
        short* __restrict__ Wlo) {
    int k = li >> 6, col = li & 63;
    int c = k >> 5, kin = k & 31;
    int g = col >> 4, nn = col & 15;
    float x = W[li];
    unsigned hb = f2bf_bits(x);
    float hf = __uint_as_float(hb << 16);
    unsigned lb = f2bf_bits(x - hf);
    int o = (((c * 4 + g) * 16 + nn) << 5) + kin;
    Whi[o] = (short)hb;
    Wlo[o] = (short)lb;
}

// ---------------- CSR build: padded-bucket counting sort ---------------------
// int4-vectorized edge reads (4 edges/load); 512 partition blocks keep the
// pass-2 per-bucket global-atomic chains at ~391 deep.

__device__ void partition_body(
        const int* __restrict__ src, const int* __restrict__ dst,
        int* __restrict__ bucketLen, int* __restrict__ pairs, int E, int nbk,
        int pb, int nb) {
    __shared__ int cnt[256];
    __shared__ int run[256];
    int t = threadIdx.x;
    int chunk = (((E + nb - 1) / nb) + 1023) & ~1023;   // multiple of 4*256
    int beg = pb * chunk;
    int end = min(beg + chunk, E);
    if (beg >= end) return;      // block-uniform exit (no divergent barrier)
    cnt[t] = 0;
    __syncthreads();

    const int4* dst4 = (const int4*)dst;
    const int4* src4 = (const int4*)src;
    int vbeg = beg >> 2;
    int vend = end >> 2;                 // beg is 4-aligned by construction
    for (int i = vbeg + t; i < vend; i += 256) {
        int4 d = dst4[i];
        atomicAdd(&cnt[d.x >> BSHIFT], 1);
        atomicAdd(&cnt[d.y >> BSHIFT], 1);
        atomicAdd(&cnt[d.z >> BSHIFT], 1);
        atomicAdd(&cnt[d.w >> BSHIFT], 1);
    }
    for (int i = (vend << 2) + t; i < end; i += 256)
        atomicAdd(&cnt[dst[i] >> BSHIFT], 1);
    __syncthreads();

    if (t < nbk) run[t] = t * BCAP + atomicAdd(&bucketLen[t], cnt[t]);
    __syncthreads();

    for (int i = vbeg + t; i < vend; i += 256) {
        int4 d = dst4[i];
        int4 s = src4[i];
        int b0 = d.x >> BSHIFT, b1 = d.y >> BSHIFT;
        int b2 = d.z >> BSHIFT, b3 = d.w >> BSHIFT;
        int s0 = atomicAdd(&run[b0], 1);
        int s1 = atomicAdd(&run[b1], 1);
        int s2 = atomicAdd(&run[b2], 1);
        int s3 = atomicAdd(&run[b3], 1);
        if (s0 < b0 * BCAP + BCAP) pairs[s0] = (s.x << BSHIFT) | (d.x & 255);
        if (s1 < b1 * BCAP + BCAP) pairs[s1] = (s.y << BSHIFT) | (d.y & 255);
        if (s2 < b2 * BCAP + BCAP) pairs[s2] = (s.z << BSHIFT) | (d.z & 255);
        if (s3 < b3 * BCAP + BCAP) pairs[s3] = (s.w << BSHIFT) | (d.w & 255);
    }
    for (int i = (vend << 2) + t; i < end; i += 256) {
        int d = dst[i];
        int slot = atomicAdd(&run[d >> BSHIFT], 1);
        if (slot < (d >> BSHIFT) * BCAP + BCAP)
            pairs[slot] = (src[i] << BSHIFT) | (d & 255);
    }
}

// fused: blocks [0,32) pack W0; blocks [32, 32+P) partition edges.
__global__ __launch_bounds__(256) void packpart_kernel(
        const float* __restrict__ W0, short* __restrict__ Whi,
        short* __restrict__ Wlo,
        const int* __restrict__ src, const int* __restrict__ dst,
        int* __restrict__ bucketLen, int* __restrict__ pairs, int E, int nbk) {
    if ((int)blockIdx.x < 32) {
        int idx = blockIdx.x * 256 + threadIdx.x;    // 8192 entries
        pack_body_w0(idx, W0, Whi, Wlo);
    } else {
        partition_body(src, dst, bucketLen, pairs, E, nbk,
                       (int)blockIdx.x - 32, (int)gridDim.x - 32);
    }
}

__device__ void csr_build_body(
        int b, const int* __restrict__ bucketLen, const int* __restrict__ pairs,
        int2* __restrict__ offdeg, int* __restrict__ csr_src, int N) {
    __shared__ int degl[256];
    __shared__ int s[256];
    __shared__ int cur[256];
    int t = threadIdx.x;
    int n0 = b << BSHIFT;
    int nodecnt = min(256, N - n0);
    int ebeg = b * BCAP;
    int eend = ebeg + bucketLen[b];

    degl[t] = 0;
    __syncthreads();
    for (int i = ebeg + t; i < eend; i += 256)
        atomicAdd(&degl[pairs[i] & 255], 1);
    __syncthreads();

    int v = degl[t];
    s[t] = v;
    __syncthreads();
    for (int o = 1; o < 256; o <<= 1) {
        int x = (t >= o) ? s[t - o] : 0;
        __syncthreads();
        s[t] += x;
        __syncthreads();
    }
    int excl = s[t] - v;
    if (t < nodecnt)
        offdeg[n0 + t] = make_int2(ebeg + excl, v);
    cur[t] = excl;
    __syncthreads();

    for (int i = ebeg + t; i < eend; i += 256) {
        int pk = pairs[i];
        int p = atomicAdd(&cur[pk & 255], 1);
        csr_src[ebeg + p] = pk >> BSHIFT;
    }
}

// ---------------- layer-0 GEMM + alpha epilogue (MFMA, split-bf16) -----------

template <int CIN, typename InT>
__device__ void gemm_body(
        int bid, const InT* __restrict__ h, const short* __restrict__ Whi,
        const short* __restrict__ Wlo,
        const float* __restrict__ a_src, const float* __restrict__ a_dst,
        __half* __restrict__ hp, float* __restrict__ as_, float* __restrict__ ad_,
        int n) {
    constexpr int KC = CIN / 32;
    int t = threadIdx.x, wave = t >> 6, lane = t & 63;
    int quad = lane >> 4, l16 = lane & 15;
    int node0 = bid * 64 + wave * 16;

    f32x4 acc[4];
#pragma unroll
    for (int g = 0; g < 4; ++g) acc[g] = (f32x4){0.f, 0.f, 0.f, 0.f};

    int nodeA = node0 + l16;
    bool va = nodeA < n;
    const InT* hrow = h + (size_t)(va ? nodeA : 0) * CIN + quad * 8;

#pragma unroll
    for (int c = 0; c < KC; ++c) {
        bf16x8 bhi[4], blo[4];
#pragma unroll
        for (int g = 0; g < 4; ++g) {
            int o = (((c * 4 + g) * 16 + l16) << 5) + quad * 8;
            bhi[g] = *(const bf16x8*)(Whi + o);
            blo[g] = *(const bf16x8*)(Wlo + o);
        }
        bf16x8 ahi, alo;
#pragma unroll
        for (int j = 0; j < 8; ++j) {
            float x = va ? to_f(hrow[c * 32 + j]) : 0.f;
            unsigned hb = f2bf_bits(x);
            float hf = __uint_as_float(hb << 16);
            unsigned lb = f2bf_bits(x - hf);
            ahi[j] = (short)hb;
            alo[j] = (short)lb;
        }
#pragma unroll
        for (int g = 0; g < 4; ++g) {
            acc[g] = __builtin_amdgcn_mfma_f32_16x16x32_bf16(ahi, bhi[g], acc[g], 0, 0, 0);
            acc[g] = __builtin_amdgcn_mfma_f32_16x16x32_bf16(ahi, blo[g], acc[g], 0, 0, 0);
            acc[g] = __builtin_amdgcn_mfma_f32_16x16x32_bf16(alo, bhi[g], acc[g], 0, 0, 0);
        }
    }

    float as4[4], ad4[4];
#pragma unroll
    for (int g = 0; g < 4; ++g) {
        as4[g] = a_src[g * 16 + l16];
        ad4[g] = a_dst[g * 16 + l16];
    }
#pragma unroll
    for (int r = 0; r < 4; ++r) {
        int node = node0 + quad * 4 + r;
        bool v = node < n;
        float vs = 0.f, vd = 0.f;
#pragma unroll
        for (int g = 0; g < 4; ++g) {
            float val = acc[g][r];
            if (v) hp[(size_t)node * 64 + g * 16 + l16] = __float2half_rn(val);
            vs = fmaf(val, as4[g], vs);
            vd = fmaf(val, ad4[g], vd);
        }
#pragma unroll
        for (int o = 1; o <= 8; o <<= 1) {
            vs += __shfl_xor(vs, o);
            vd += __shfl_xor(vd, o);
        }
        if (v && l16 == 0) {
            as_[node] = vs;
            ad_[node] = vd;
        }
    }
}

__global__ __launch_bounds__(256) void csr_gemm0_kernel(
        const int* __restrict__ bucketLen, const int* __restrict__ pairs,
        int2* __restrict__ offdeg, int* __restrict__ csr_src,
        int N, int nbk,
        const float* __restrict__ x, const short* __restrict__ Whi,
        const short* __restrict__ Wlo, const float* __restrict__ a_src,
        const float* __restrict__ a_dst, __half* __restrict__ hp,
        float* __restrict__ as_, float* __restrict__ ad_) {
    if ((int)blockIdx.x < nbk)
        csr_build_body(blockIdx.x, bucketLen, pairs, offdeg, csr_src, N);
    else
        gemm_body<128, float>((int)blockIdx.x - nbk, x, Whi, Wlo,
                              a_src, a_dst, hp, as_, ad_, N);
}

// ---------------- agg (+ fused next-layer GEMM epilogue) ---------------------
// Verified-best configuration (round 7, 241.3 us). Two nodes per wave (32
// lanes each). Critical-path minimized:
//  - no max-subtraction (softmax is shift-invariant; logits are O(1), f32-safe)
//  - as_ logit gather issued FIRST, hp rows right after
//  - bias/asn/adn tail operands hoisted to issue alongside the gathers
//  - src/weight cross-lane exchange via __shfl (registers), no LDS round-trip
//  - W tile staged in LDS at block start (R8: W-from-global regressed 45->72;
//    R10: deferring the staging barrier past the agg phase regressed 45->53)
// For !FINAL, the finished 64-wide row round-trips through wave-local LDS and
// the next layer's 64x64 GEMM runs as a VALU epilogue writing hp/as/ad next.

__device__ __forceinline__ void h8_to_f(uint4 u, float* f) {
    __half2 a = *(__half2*)&u.x;
    __half2 b = *(__half2*)&u.y;
    __half2 c = *(__half2*)&u.z;
    __half2 d = *(__half2*)&u.w;
    float2 f01 = __half22float2(a);
    float2 f23 = __half22float2(b);
    float2 f45 = __half22float2(c);
    float2 f67 = __half22float2(d);
    f[0] = f01.x; f[1] = f01.y; f[2] = f23.x; f[3] = f23.y;
    f[4] = f45.x; f[5] = f45.y; f[6] = f67.x; f[7] = f67.y;
}

__device__ __forceinline__ uint4 pack8h(const float* v) {
    __half2 h0 = __floats2half2_rn(v[0], v[1]);
    __half2 h1 = __floats2half2_rn(v[2], v[3]);
    __half2 h2 = __floats2half2_rn(v[4], v[5]);
    __half2 h3 = __floats2half2_rn(v[6], v[7]);
    uint4 u;
    u.x = *(unsigned*)&h0; u.y = *(unsigned*)&h1;
    u.z = *(unsigned*)&h2; u.w = *(unsigned*)&h3;
    return u;
}

template <bool FINAL>
__global__ __launch_bounds__(256) void agg_fused_kernel(
        const __half* __restrict__ hp_in,
        const float* __restrict__ as_in, const float* __restrict__ ad_in,
        const int2* __restrict__ offdeg, const int* __restrict__ csr_src,
        const float* __restrict__ bias,
        const float* __restrict__ Wn,                  // next-layer W, f32 64x64
        const float* __restrict__ asn, const float* __restrict__ adn,
        __half* __restrict__ hp_out, float* __restrict__ as_out,
        float* __restrict__ ad_out, float* __restrict__ final_out, int n) {
    __shared__ __half rowT[8][64];
    __shared__ float Wl[FINAL ? 4 : 4096];

    int t = threadIdx.x;
    if constexpr (!FINAL) {
        const float4* wg = (const float4*)Wn;
        float4* wl = (float4*)Wl;
#pragma unroll
        for (int i = 0; i < 4; ++i) wl[t + 256 * i] = wg[t + 256 * i];
        __syncthreads();
    }

    int wave = t >> 6, lane = t & 63;
    int hf = lane >> 5, l32 = lane & 31;
    int node = blockIdx.x * 8 + wave * 2 + hf;
    int slot = wave * 2 + hf;
    if (node >= n) return;

    int2 od = offdeg[node];

    // hoisted tail operands (independent loads; consumed after accumulate)
    float es0 = 0.f, es1 = 0.f, ed0 = 0.f, ed1 = 0.f;
    if constexpr (!FINAL) {
        int c0 = l32 * 2;
        es0 = asn[c0]; es1 = asn[c0 + 1];
        ed0 = adn[c0]; ed1 = adn[c0 + 1];
    }

    int beg = od.x;
    int deg = od.y;
    float adst = ad_in[node];
    float e_self = leaky(as_in[node] + adst);
    float pself = __expf(e_self);

    if (deg <= 32) {
        bool valid = l32 < deg;
        int s = valid ? csr_src[beg + l32] : 0;
        float as_s = valid ? as_in[s] : 0.f;       // critical gather: issue 1st

        int g8 = l32 >> 3, s8 = l32 & 7;
        int base = hf * 32;
        const uint4* hp4 = (const uint4*)hp_in;    // row = 8 x uint4 (64 halves)

        // hoisted bias (all lanes load; only g8==0 consumes)
        const float4* b4p = (const float4*)bias;
        float4 ba = b4p[s8 * 2], bb = b4p[s8 * 2 + 1];

        // ---- pre-issue ALL gather rows (src values via register shfl)
        uint4 u8[8];
#pragma unroll
        for (int q = 0; q < 8; ++q) {
            int jj = g8 + 4 * q;
            int sj = __shfl(s, base + jj);
            if (jj < deg) u8[q] = hp4[(size_t)sj * 8 + s8];
        }
        uint4 uself = (g8 == 0) ? hp4[(size_t)node * 8 + s8]
                                : make_uint4(0u, 0u, 0u, 0u);

        // ---- softmax (no max-shift) — overlaps the in-flight loads
        float p = valid ? __expf(leaky(as_s + adst)) : 0.f;
        float se = p;
#pragma unroll
        for (int o = 16; o > 0; o >>= 1) se += __shfl_xor(se, o);
        se += pself;
        float inv = 1.0f / (se + 1e-16f);
        float pin = p * inv;

        // ---- weighted accumulate (weights via shfl; loads have landed)
        float acc[8];
        float wself = (g8 == 0) ? pself * inv : 0.f;
        {
            float fs[8];
            h8_to_f(uself, fs);
#pragma unroll
            for (int i = 0; i < 8; ++i) acc[i] = wself * fs[i];
        }
#pragma unroll
        for (int q = 0; q < 8; ++q) {
            int jj = g8 + 4 * q;
            float w = __shfl(pin, base + jj);
            if (jj < deg) {
                float f8[8];
                h8_to_f(u8[q], f8);
#pragma unroll
                for (int i = 0; i < 8; ++i) acc[i] = fmaf(w, f8[i], acc[i]);
            }
        }

        // reduce across the 4 groups of this half
#pragma unroll
        for (int i = 0; i < 8; ++i) {
            acc[i] += __shfl_xor(acc[i], 8);
            acc[i] += __shfl_xor(acc[i], 16);
        }

        if (g8 == 0) {
            float v[8];
            v[0] = acc[0] + ba.x; v[1] = acc[1] + ba.y;
            v[2] = acc[2] + ba.z; v[3] = acc[3] + ba.w;
            v[4] = acc[4] + bb.x; v[5] = acc[5] + bb.y;
            v[6] = acc[6] + bb.z; v[7] = acc[7] + bb.w;
#pragma unroll
            for (int i = 0; i < 8; ++i) v[i] = v[i] > 0.f ? v[i] : 0.f;
            if constexpr (FINAL) {
                float4 ra, rb;
                ra.x = v[0]; ra.y = v[1]; ra.z = v[2]; ra.w = v[3];
                rb.x = v[4]; rb.y = v[5]; rb.z = v[6]; rb.w = v[7];
                ((float4*)final_out)[(size_t)node * 16 + s8 * 2] = ra;
                ((float4*)final_out)[(size_t)node * 16 + s8 * 2 + 1] = rb;
            } else {
                ((uint4*)&rowT[slot][0])[s8] = pack8h(v);
            }
        }
    } else {
        // 32-lane strided fallback (P(deg>32) ~ 8e-5 per node); no max-shift
        int end = beg + deg;
        float se = 0.f;
        for (int i = beg + l32; i < end; i += 32) {
            int s = csr_src[i];
            se += __expf(leaky(as_in[s] + adst));
        }
#pragma unroll
        for (int o = 16; o > 0; o >>= 1) se += __shfl_xor(se, o);
        se += pself;
        float inv = 1.0f / (se + 1e-16f);

        const __half2* hpx = (const __half2*)hp_in;   // row = 32 x half2
        float2 hs = __half22float2(hpx[(size_t)node * 32 + l32]);
        float wself = pself * inv;
        float a0 = wself * hs.x, a1 = wself * hs.y;
        for (int i = beg; i < end; ++i) {
            int s = csr_src[i];
            float w = __expf(leaky(as_in[s] + adst)) * inv;
            float2 hv = __half22float2(hpx[(size_t)s * 32 + l32]);
            a0 = fmaf(w, hv.x, a0);
            a1 = fmaf(w, hv.y, a1);
        }
        float r0 = a0 + bias[l32 * 2];
        float r1 = a1 + bias[l32 * 2 + 1];
        r0 = r0 > 0.f ? r0 : 0.f;
        r1 = r1 > 0.f ? r1 : 0.f;
        if constexpr (FINAL) {
            final_out[(size_t)node * 64 + l32 * 2]     = r0;
            final_out[(size_t)node * 64 + l32 * 2 + 1] = r1;
        } else {
            *(__half2*)&rowT[slot][l32 * 2] = __floats2half2_rn(r0, r1);
        }
    }

    // ---- fused next-layer GEMM epilogue (wave-local; W in LDS) ----
    if constexpr (!FINAL) {
        const float2* W2p = (const float2*)Wl;        // [64][32] float2
        const uint4* row4 = (const uint4*)&rowT[slot][0];
        float a0 = 0.f, a1 = 0.f;
#pragma unroll
        for (int kk = 0; kk < 8; ++kk) {
            float f8[8];
            h8_to_f(row4[kk], f8);
#pragma unroll
            for (int j = 0; j < 8; ++j) {
                float2 w = W2p[(kk * 8 + j) * 32 + l32];
                a0 = fmaf(f8[j], w.x, a0);
                a1 = fmaf(f8[j], w.y, a1);
            }
        }
        ((__half2*)hp_out)[(size_t)node * 32 + l32] = __floats2half2_rn(a0, a1);
        float vs = fmaf(a0, es0, a1 * es1);
        float vd = fmaf(a0, ed0, a1 * ed1);
#pragma unroll
        for (int o = 1; o <= 16; o <<= 1) {
            vs += __shfl_xor(vs, o);
            vd += __shfl_xor(vd, o);
        }
        if (l32 == 0) {
            as_out[node] = vs;
            ad_out[node] = vd;
        }
    }
}

// ---------------- launch ----------------

extern "C" void kernel_launch(void* const* d_in, const int* in_sizes, int n_in,
                              void* d_out, int out_size, void* d_ws, size_t ws_size,
                              hipStream_t stream) {
    const float* x = (const float*)d_in[0];
    const int* edge_index = (const int*)d_in[1];
    const int N = in_sizes[0] / 128;
    const int E = in_sizes[1] / 2;
    const int NBK = (N + 255) >> BSHIFT;

    const float* W[3]    = {(const float*)d_in[4], (const float*)d_in[8],  (const float*)d_in[12]};
    const float* asrc[3] = {(const float*)d_in[5], (const float*)d_in[9],  (const float*)d_in[13]};
    const float* adst[3] = {(const float*)d_in[6], (const float*)d_in[10], (const float*)d_in[14]};
    const float* bias[3] = {(const float*)d_in[7], (const float*)d_in[11], (const float*)d_in[15]};

    char* ws = (char*)d_ws;
    size_t o = 0;
    auto alloc = [&](size_t bytes) {
        char* p = ws + o;
        o += (bytes + 255) & ~(size_t)255;
        return p;
    };
    int* bucketLen    = (int*)alloc(256 * 4);
    int* pairs        = (int*)alloc((size_t)NBK * BCAP * 4);
    int2* offdeg      = (int2*)alloc((size_t)N * 8);
    int* csr_src      = (int*)alloc((size_t)NBK * BCAP * 4);
    float* asA        = (float*)alloc((size_t)N * 4);
    float* adA        = (float*)alloc((size_t)N * 4);
    float* asB        = (float*)alloc((size_t)N * 4);
    float* adB        = (float*)alloc((size_t)N * 4);
    __half* hpA       = (__half*)alloc((size_t)N * 64 * 2);
    __half* hpB       = (__half*)alloc((size_t)N * 64 * 2);
    short* Whi        = (short*)alloc(8192 * 2);
    short* Wlo        = (short*)alloc(8192 * 2);

    const int* srcp = edge_index;
    const int* dstp = edge_index + E;

    int gb = (N + 63) / 64;    // 64-node GEMM tiles (layer 0)
    int ab = (N + 7) / 8;      // 8-node agg blocks

    hipMemsetAsync(bucketLen, 0, 256 * sizeof(int), stream);

    // pack W0 || partition edges (independent blocks, one dispatch)
    packpart_kernel<<<32 + 512, 256, 0, stream>>>(
        W[0], Whi, Wlo, srcp, dstp, bucketLen, pairs, E, NBK);

    // csr build || layer-0 GEMM  ->  hpA, asA, adA
    csr_gemm0_kernel<<<NBK + gb, 256, 0, stream>>>(
        bucketLen, pairs, offdeg, csr_src, N, NBK,
        x, Whi, Wlo, asrc[0], adst[0], hpA, asA, adA);

    // agg layer 0 + fused gemm1  ->  hpB, asB, adB
    agg_fused_kernel<false><<<ab, 256, 0, stream>>>(
        hpA, asA, adA, offdeg, csr_src, bias[0],
        W[1], asrc[1], adst[1], hpB, asB, adB, nullptr, N);

    // agg layer 1 + fused gemm2  ->  hpA, asA, adA
    agg_fused_kernel<false><<<ab, 256, 0, stream>>>(
        hpB, asB, adB, offdeg, csr_src, bias[1],
        W[2], asrc[2], adst[2], hpA, asA, adA, nullptr, N);

    // agg layer 2 -> final f32 output
    agg_fused_kernel<true><<<ab, 256, 0, stream>>>(
        hpA, asA, adA, offdeg, csr_src, bias[2],
        nullptr, nullptr, nullptr, nullptr, nullptr, nullptr,
        (float*)d_out, N);
}